// Round 2
// baseline (1324.465 us; speedup 1.0000x reference)
//
#include <hip/hip_runtime.h>
#include <cstdint>
#include <cstddef>

#define Bb 8
#define Tt 4096
#define Dd 1024
#define DS 64
#define Mm (Bb*Tt)   // 32768

// ---------------------------------------------------------------------------
// Kernel 1: QKV projection. qkv[M][192] = X[M][1024] @ W^T + bias
// cols 0..63 = q, 64..127 = k, 128..191 = v
// block 256 threads, BM=64, BN=192, BK=32
// ---------------------------------------------------------------------------
__global__ __launch_bounds__(256) void qkv_gemm(
    const float* __restrict__ x,
    const float* __restrict__ Wq, const float* __restrict__ bq,
    const float* __restrict__ Wk, const float* __restrict__ bk,
    const float* __restrict__ Wv, const float* __restrict__ bv,
    float* __restrict__ qkv)
{
  __shared__ float xs[64 * 36];      // [row][k], padded stride 36 (16B-aligned rows)
  __shared__ float wsh[32 * 192];    // [k][col] transposed tile

  const int t  = threadIdx.x;
  const int m0 = blockIdx.x * 64;
  const int tr = t >> 4;             // 0..15 -> 4 rows each
  const int tc = t & 15;             // 0..15 -> 12 cols each

  // per-thread bias for its 12 columns
  float bias[12];
  #pragma unroll
  for (int cc = 0; cc < 12; ++cc) {
    int j = tc * 12 + cc;
    bias[cc] = (j < 64) ? bq[j] : ((j < 128) ? bk[j - 64] : bv[j - 128]);
  }

  float acc[4][12] = {};

  for (int kb = 0; kb < 1024; kb += 32) {
    // stage X tile: 64 rows x 32 k = 512 float4
    #pragma unroll
    for (int i = 0; i < 2; ++i) {
      int idx = t + i * 256;
      int row = idx >> 3, f = idx & 7;
      float4 g = *(const float4*)(x + (size_t)(m0 + row) * 1024 + kb + f * 4);
      *(float4*)(&xs[row * 36 + f * 4]) = g;
    }
    // stage W tile transposed: 192 cols x 32 k = 1536 float4
    #pragma unroll
    for (int i = 0; i < 6; ++i) {
      int idx = t + i * 256;
      int c = idx >> 3, f = idx & 7;
      const float* wrow = (c < 64) ? (Wq + (size_t)c * 1024)
                        : ((c < 128) ? (Wk + (size_t)(c - 64) * 1024)
                                     : (Wv + (size_t)(c - 128) * 1024));
      float4 g = *(const float4*)(wrow + kb + f * 4);
      wsh[(f * 4 + 0) * 192 + c] = g.x;
      wsh[(f * 4 + 1) * 192 + c] = g.y;
      wsh[(f * 4 + 2) * 192 + c] = g.z;
      wsh[(f * 4 + 3) * 192 + c] = g.w;
    }
    __syncthreads();

    #pragma unroll
    for (int kk = 0; kk < 32; ++kk) {
      float xv[4];
      #pragma unroll
      for (int r = 0; r < 4; ++r) xv[r] = xs[(tr * 4 + r) * 36 + kk];
      float wv[12];
      #pragma unroll
      for (int g = 0; g < 3; ++g) {
        float4 w4 = *(const float4*)(&wsh[kk * 192 + tc * 12 + g * 4]);
        wv[g * 4 + 0] = w4.x; wv[g * 4 + 1] = w4.y;
        wv[g * 4 + 2] = w4.z; wv[g * 4 + 3] = w4.w;
      }
      #pragma unroll
      for (int r = 0; r < 4; ++r)
        #pragma unroll
        for (int c = 0; c < 12; ++c)
          acc[r][c] = fmaf(xv[r], wv[c], acc[r][c]);
    }
    __syncthreads();
  }

  // epilogue: add bias, store
  #pragma unroll
  for (int r = 0; r < 4; ++r) {
    size_t m = (size_t)m0 + tr * 4 + r;
    float* dst = qkv + m * 192 + tc * 12;
    #pragma unroll
    for (int g = 0; g < 3; ++g) {
      float4 o;
      o.x = acc[r][g * 4 + 0] + bias[g * 4 + 0];
      o.y = acc[r][g * 4 + 1] + bias[g * 4 + 1];
      o.z = acc[r][g * 4 + 2] + bias[g * 4 + 2];
      o.w = acc[r][g * 4 + 3] + bias[g * 4 + 3];
      *(float4*)(dst + g * 4) = o;
    }
  }
}

// ---------------------------------------------------------------------------
// Kernel 2: sequential scan. One wave per (b, i-pair). Lane layout:
//   il = lane>>5 (which of 2 i's), jp = lane&31, lane owns j = jp*2, jp*2+1.
// q/k/v staged in 32-step chunks via global_load_lds, double-buffered.
// ---------------------------------------------------------------------------
#define CT 32                       // chunk of timesteps
#define CHUNK_FLOATS (CT * 192)     // 6144 floats = 24KB

__device__ __forceinline__ void stage_chunk(const float* g, float* l, int lane) {
  #pragma unroll
  for (int j = 0; j < 24; ++j) {
    __builtin_amdgcn_global_load_lds(
        (const __attribute__((address_space(1))) void*)(g + j * 256 + lane * 4),
        (__attribute__((address_space(3))) void*)(l + j * 256),
        16, 0, 0);
  }
}

__global__ __launch_bounds__(64) void scan_kernel(
    const float* __restrict__ qkv, const float* __restrict__ decay,
    float* __restrict__ sout)
{
  __shared__ float buf[2 * CHUNK_FLOATS];   // 48KB

  const int lane = threadIdx.x;
  const int b  = blockIdx.x >> 5;
  const int i0 = (blockIdx.x & 31) * 2;
  const int il = lane >> 5;
  const int jp = lane & 31;
  const int i  = i0 + il;

  const float dec = decay[i];
  const float d = 1.0f / (1.0f + expf(-dec));

  const float* src = qkv + (size_t)b * Tt * 192;

  stage_chunk(src, &buf[0], lane);

  float S0 = 0.f, S1 = 0.f;
  int cur = 0;

  for (int c = 0; c < Tt / CT; ++c) {
    asm volatile("s_waitcnt vmcnt(0)" ::: "memory");
    if (c < Tt / CT - 1)
      stage_chunk(src + (size_t)(c + 1) * CHUNK_FLOATS, &buf[(cur ^ 1) * CHUNK_FLOATS], lane);

    const int bb = cur * CHUNK_FLOATS;
    #pragma unroll
    for (int u = 0; u < CT; ++u) {
      float2 kv = *(const float2*)(&buf[bb + u * 192 + 64 + jp * 2]);
      float2 qv = *(const float2*)(&buf[bb + u * 192 + jp * 2]);
      float  vv = buf[bb + u * 192 + 128 + i];
      S0 = fmaf(d, S0, vv * kv.x);
      S1 = fmaf(d, S1, vv * kv.y);
      float p = fmaf(S1, qv.y, S0 * qv.x);
      p += __shfl_xor(p, 1);
      p += __shfl_xor(p, 2);
      p += __shfl_xor(p, 4);
      p += __shfl_xor(p, 8);
      p += __shfl_xor(p, 16);
      if (jp == 0) {
        int tt = c * CT + u;
        sout[((size_t)(b * Tt + tt)) * 64 + i] = p;
      }
    }
    cur ^= 1;
  }
}

// ---------------------------------------------------------------------------
// Kernel 3: out[M][1024] = x + scan_out[M][64] @ Wo^T + bo
// block 256 threads, BM=128 rows, BN=256 cols, K=64
// ---------------------------------------------------------------------------
__global__ __launch_bounds__(256) void out_gemm(
    const float* __restrict__ x, const float* __restrict__ so,
    const float* __restrict__ Wo, const float* __restrict__ bo,
    float* __restrict__ out)
{
  __shared__ float wsh[64 * 256];   // [k][c] 64KB
  __shared__ float ssh[16 * 64];    // [r][k] 4KB

  const int t   = threadIdx.x;
  const int cb  = blockIdx.x & 3;
  const int c0  = cb * 256;
  const int rb0 = (blockIdx.x >> 2) * 128;

  // stage Wo transposed: thread t owns column c0+t
  {
    const float* wrow = Wo + (size_t)(c0 + t) * 64;
    #pragma unroll
    for (int f = 0; f < 16; ++f) {
      float4 g = *(const float4*)(wrow + f * 4);
      wsh[(f * 4 + 0) * 256 + t] = g.x;
      wsh[(f * 4 + 1) * 256 + t] = g.y;
      wsh[(f * 4 + 2) * 256 + t] = g.z;
      wsh[(f * 4 + 3) * 256 + t] = g.w;
    }
  }

  const int tc = t & 63, tr = t >> 6;
  float4 bo4 = *(const float4*)(bo + c0 + tc * 4);
  __syncthreads();

  for (int rb = 0; rb < 8; ++rb) {
    __syncthreads();
    // stage 16 rows of scan_out (16*64 = 1024 floats = 256 float4)
    {
      float4 g = ((const float4*)(so + (size_t)(rb0 + rb * 16) * 64))[t];
      *(float4*)(&ssh[t * 4]) = g;
    }
    __syncthreads();

    float acc[4][4] = {};
    #pragma unroll
    for (int k = 0; k < 64; ++k) {
      float4 w4 = *(const float4*)(&wsh[k * 256 + tc * 4]);
      #pragma unroll
      for (int rr = 0; rr < 4; ++rr) {
        float sv = ssh[(tr * 4 + rr) * 64 + k];
        acc[rr][0] = fmaf(sv, w4.x, acc[rr][0]);
        acc[rr][1] = fmaf(sv, w4.y, acc[rr][1]);
        acc[rr][2] = fmaf(sv, w4.z, acc[rr][2]);
        acc[rr][3] = fmaf(sv, w4.w, acc[rr][3]);
      }
    }

    #pragma unroll
    for (int rr = 0; rr < 4; ++rr) {
      size_t m = (size_t)rb0 + rb * 16 + tr * 4 + rr;
      const float4 xv = *(const float4*)(x + m * 1024 + c0 + tc * 4);
      float4 o;
      o.x = xv.x + acc[rr][0] + bo4.x;
      o.y = xv.y + acc[rr][1] + bo4.y;
      o.z = xv.z + acc[rr][2] + bo4.z;
      o.w = xv.w + acc[rr][3] + bo4.w;
      *(float4*)(out + m * 1024 + c0 + tc * 4) = o;
    }
  }
}

// ---------------------------------------------------------------------------
extern "C" void kernel_launch(void* const* d_in, const int* in_sizes, int n_in,
                              void* d_out, int out_size, void* d_ws, size_t ws_size,
                              hipStream_t stream)
{
  const float* x   = (const float*)d_in[0];
  const float* Wq  = (const float*)d_in[1];
  const float* bq  = (const float*)d_in[2];
  const float* Wk  = (const float*)d_in[3];
  const float* bk  = (const float*)d_in[4];
  const float* Wv  = (const float*)d_in[5];
  const float* bv  = (const float*)d_in[6];
  const float* dec = (const float*)d_in[7];
  const float* Wo  = (const float*)d_in[8];
  const float* bo  = (const float*)d_in[9];
  float* out = (float*)d_out;

  float* qkv = (float*)d_ws;                 // [M][192] fp32 = 25.2 MB
  float* so  = qkv + (size_t)Mm * 192;       // [M][64]  fp32 = 8.4 MB

  qkv_gemm<<<Mm / 64, 256, 0, stream>>>(x, Wq, bq, Wk, bk, Wv, bv, qkv);
  scan_kernel<<<256, 64, 0, stream>>>(qkv, dec, so);
  out_gemm<<<(Mm / 128) * 4, 256, 0, stream>>>(x, so, Wo, bo, out);
}

// Round 5
// 504.075 us; speedup vs baseline: 2.6275x; 2.6275x over previous
//
#include <hip/hip_runtime.h>
#include <cstdint>
#include <cstddef>
#include <cmath>

#define Bb 8
#define Tt 4096
#define Dd 1024
#define DS 64
#define Mm (Bb*Tt)   // 32768
#define PAD 68       // floats per LDS row (16B-aligned rows: 68*4=272B)

// float4 pointer into a [64][PAD] LDS tile at logical (row, col4),
// XOR-swizzled so column-slice reads spread across banks.
__device__ __forceinline__ float4* ldsP(float* buf, int row, int col4) {
  return (float4*)(buf + row * PAD + (((col4) ^ ((row >> 3) & 7)) << 2));
}

// ---------------------------------------------------------------------------
// Kernel 1: QKV projection. qkv[M][192] = X[M][1024] @ W^T + bias (unchanged)
// ---------------------------------------------------------------------------
__global__ __launch_bounds__(256) void qkv_gemm(
    const float* __restrict__ x,
    const float* __restrict__ Wq, const float* __restrict__ bq,
    const float* __restrict__ Wk, const float* __restrict__ bk,
    const float* __restrict__ Wv, const float* __restrict__ bv,
    float* __restrict__ qkv)
{
  __shared__ float xs[64 * 36];
  __shared__ float wsh[32 * 192];

  const int t  = threadIdx.x;
  const int m0 = blockIdx.x * 64;
  const int tr = t >> 4;
  const int tc = t & 15;

  float bias[12];
  #pragma unroll
  for (int cc = 0; cc < 12; ++cc) {
    int j = tc * 12 + cc;
    bias[cc] = (j < 64) ? bq[j] : ((j < 128) ? bk[j - 64] : bv[j - 128]);
  }

  float acc[4][12] = {};

  for (int kb = 0; kb < 1024; kb += 32) {
    #pragma unroll
    for (int i = 0; i < 2; ++i) {
      int idx = t + i * 256;
      int row = idx >> 3, f = idx & 7;
      float4 g = *(const float4*)(x + (size_t)(m0 + row) * 1024 + kb + f * 4);
      *(float4*)(&xs[row * 36 + f * 4]) = g;
    }
    #pragma unroll
    for (int i = 0; i < 6; ++i) {
      int idx = t + i * 256;
      int c = idx >> 3, f = idx & 7;
      const float* wrow = (c < 64) ? (Wq + (size_t)c * 1024)
                        : ((c < 128) ? (Wk + (size_t)(c - 64) * 1024)
                                     : (Wv + (size_t)(c - 128) * 1024));
      float4 g = *(const float4*)(wrow + kb + f * 4);
      wsh[(f * 4 + 0) * 192 + c] = g.x;
      wsh[(f * 4 + 1) * 192 + c] = g.y;
      wsh[(f * 4 + 2) * 192 + c] = g.z;
      wsh[(f * 4 + 3) * 192 + c] = g.w;
    }
    __syncthreads();

    #pragma unroll
    for (int kk = 0; kk < 32; ++kk) {
      float xv[4];
      #pragma unroll
      for (int r = 0; r < 4; ++r) xv[r] = xs[(tr * 4 + r) * 36 + kk];
      float wv[12];
      #pragma unroll
      for (int g = 0; g < 3; ++g) {
        float4 w4 = *(const float4*)(&wsh[kk * 192 + tc * 12 + g * 4]);
        wv[g * 4 + 0] = w4.x; wv[g * 4 + 1] = w4.y;
        wv[g * 4 + 2] = w4.z; wv[g * 4 + 3] = w4.w;
      }
      #pragma unroll
      for (int r = 0; r < 4; ++r)
        #pragma unroll
        for (int c = 0; c < 12; ++c)
          acc[r][c] = fmaf(xv[r], wv[c], acc[r][c]);
    }
    __syncthreads();
  }

  #pragma unroll
  for (int r = 0; r < 4; ++r) {
    size_t m = (size_t)m0 + tr * 4 + r;
    float* dst = qkv + m * 192 + tc * 12;
    #pragma unroll
    for (int g = 0; g < 3; ++g) {
      float4 o;
      o.x = acc[r][g * 4 + 0] + bias[g * 4 + 0];
      o.y = acc[r][g * 4 + 1] + bias[g * 4 + 1];
      o.z = acc[r][g * 4 + 2] + bias[g * 4 + 2];
      o.w = acc[r][g * 4 + 3] + bias[g * 4 + 3];
      *(float4*)(dst + g * 4) = o;
    }
  }
}

// ---------------------------------------------------------------------------
// Phase A: per (b,chunk): G = causal(Q K^T) (stored transposed GT[s][u]),
//   Vt[s,i] = v_s[i] * d_i^{-s},
//   U[i,j]  = d_i^63 * sum_s Vt[s,i] K[s,j]      -> Ubuf
//   intra[u,i] = d_i^u * sum_s GT[s,u] Vt[s,i]   -> so (phase C adds to it)
// Block = 256 threads = 16x16 grid of 4x4 register tiles.
// ---------------------------------------------------------------------------
__global__ __launch_bounds__(256) void scan_chunk_a(
    const float* __restrict__ qkv, const float* __restrict__ decay,
    float* __restrict__ Ubuf, float* __restrict__ so)
{
  __shared__ float Qs[64 * PAD];   // later overwritten with GT
  __shared__ float Ks[64 * PAD];
  __shared__ float Vs[64 * PAD];   // scaled to Vt in place
  __shared__ float l2d[64];

  const int tid = threadIdx.x;
  const int bc  = blockIdx.x;          // b*64 + ch
  const int b   = bc >> 6;
  const int ch  = bc & 63;
  const int ti  = tid >> 4;            // 0..15 (tile row)
  const int tj  = tid & 15;            // 0..15 (tile col)

  const float* base = qkv + ((size_t)(b * Tt + ch * 64)) * 192;

  // stage Q,K,V (64 rows x 48 float4)
  #pragma unroll
  for (int it = 0; it < 12; ++it) {
    int idx = tid + it * 256;
    int row = idx / 48, f = idx % 48;
    float4 g = *(const float4*)(base + (size_t)row * 192 + f * 4);
    float4* dst;
    if (f < 16)      dst = ldsP(Qs, row, f);
    else if (f < 32) dst = ldsP(Ks, row, f - 16);
    else             dst = ldsP(Vs, row, f - 32);
    *dst = g;
  }
  if (tid < 64) {
    float d = 1.0f / (1.0f + expf(-decay[tid]));
    l2d[tid] = log2f(d);
  }
  __syncthreads();

  // Vt scale in place: thread owns row s = tid>>2, 4 float4
  {
    int s = tid >> 2;
    #pragma unroll
    for (int g4 = 0; g4 < 4; ++g4) {
      int col4 = (tid & 3) * 4 + g4;
      float4* p = ldsP(Vs, s, col4);
      float4 v = *p;
      float e0 = exp2f(-(float)s * l2d[col4 * 4 + 0]);
      float e1 = exp2f(-(float)s * l2d[col4 * 4 + 1]);
      float e2 = exp2f(-(float)s * l2d[col4 * 4 + 2]);
      float e3 = exp2f(-(float)s * l2d[col4 * 4 + 3]);
      v.x *= e0; v.y *= e1; v.z *= e2; v.w *= e3;
      *p = v;
    }
  }

  // G tile in registers: gval[r][c] = k_{s=ti*4+r} . q_{u=tj*4+c}, causal
  float gval[4][4] = {};
  #pragma unroll
  for (int kk4 = 0; kk4 < 16; ++kk4) {
    float4 K4[4], Q4[4];
    #pragma unroll
    for (int r = 0; r < 4; ++r) K4[r] = *ldsP(Ks, ti * 4 + r, kk4);
    #pragma unroll
    for (int c = 0; c < 4; ++c) Q4[c] = *ldsP(Qs, tj * 4 + c, kk4);
    #pragma unroll
    for (int r = 0; r < 4; ++r)
      #pragma unroll
      for (int c = 0; c < 4; ++c) {
        gval[r][c] = fmaf(K4[r].x, Q4[c].x, gval[r][c]);
        gval[r][c] = fmaf(K4[r].y, Q4[c].y, gval[r][c]);
        gval[r][c] = fmaf(K4[r].z, Q4[c].z, gval[r][c]);
        gval[r][c] = fmaf(K4[r].w, Q4[c].w, gval[r][c]);
      }
  }
  // causal mask: keep if s <= u
  #pragma unroll
  for (int r = 0; r < 4; ++r)
    #pragma unroll
    for (int c = 0; c < 4; ++c)
      if (ti * 4 + r > tj * 4 + c) gval[r][c] = 0.0f;

  __syncthreads();   // all Q reads done; Vt writes visible

  // write GT into Qs: GT[s = ti*4+r][u-col4 = tj]
  #pragma unroll
  for (int r = 0; r < 4; ++r) {
    float4 g4 = {gval[r][0], gval[r][1], gval[r][2], gval[r][3]};
    *ldsP(Qs, ti * 4 + r, tj) = g4;
  }
  __syncthreads();

  // fused s-loop: uacc[i=ti*4+r][j=tj*4+c], oacc[u=ti*4+r][i=tj*4+c]
  float uacc[4][4] = {};
  float oacc[4][4] = {};
  for (int s = 0; s < 64; ++s) {
    float4 Vti = *ldsP(Vs, s, ti);   // Vt[s][ti*4 .. +3]
    float4 Ktj = *ldsP(Ks, s, tj);   // K [s][tj*4 .. +3]
    float4 Gti = *ldsP(Qs, s, ti);   // GT[s][ti*4 .. +3]
    float4 Vtj = *ldsP(Vs, s, tj);   // Vt[s][tj*4 .. +3]
    const float vi[4] = {Vti.x, Vti.y, Vti.z, Vti.w};
    const float kj[4] = {Ktj.x, Ktj.y, Ktj.z, Ktj.w};
    const float gu[4] = {Gti.x, Gti.y, Gti.z, Gti.w};
    const float vj[4] = {Vtj.x, Vtj.y, Vtj.z, Vtj.w};
    #pragma unroll
    for (int r = 0; r < 4; ++r)
      #pragma unroll
      for (int c = 0; c < 4; ++c) {
        uacc[r][c] = fmaf(vi[r], kj[c], uacc[r][c]);
        oacc[r][c] = fmaf(gu[r], vj[c], oacc[r][c]);
      }
  }

  // write U[i][j] * d_i^63
  #pragma unroll
  for (int r = 0; r < 4; ++r) {
    int i = ti * 4 + r;
    float d63 = exp2f(63.0f * l2d[i]);
    float4 o = {uacc[r][0] * d63, uacc[r][1] * d63,
                uacc[r][2] * d63, uacc[r][3] * d63};
    *(float4*)(Ubuf + ((size_t)bc * 64 + i) * 64 + tj * 4) = o;
  }
  // write intra[u][i] = oacc * d_i^u  into so
  #pragma unroll
  for (int r = 0; r < 4; ++r) {
    int u = ti * 4 + r;
    float e0 = exp2f((float)u * l2d[tj * 4 + 0]);
    float e1 = exp2f((float)u * l2d[tj * 4 + 1]);
    float e2 = exp2f((float)u * l2d[tj * 4 + 2]);
    float e3 = exp2f((float)u * l2d[tj * 4 + 3]);
    float4 o = {oacc[r][0] * e0, oacc[r][1] * e1,
                oacc[r][2] * e2, oacc[r][3] * e3};
    *(float4*)(so + ((size_t)(b * Tt + ch * 64 + u)) * 64 + tj * 4) = o;
  }
}

// ---------------------------------------------------------------------------
// Phase B: sequential over chunks (64 steps), parallel over (b, i, j).
// In-place: Ubuf slot c is read (prefetch c+1 before store c) then
// overwritten with S_start(c). 32 blocks x 256 threads, 1 float4 each.
// ---------------------------------------------------------------------------
__global__ __launch_bounds__(256) void scan_state(
    const float* __restrict__ decay, float* __restrict__ Ubuf)
{
  const int b  = blockIdx.x >> 2;
  const int jq = blockIdx.x & 3;
  const int i  = threadIdx.x >> 2;
  const int j4 = threadIdx.x & 3;

  float d = 1.0f / (1.0f + expf(-decay[i]));
  float d2 = d * d, d4 = d2 * d2, d8 = d4 * d4;
  float d16 = d8 * d8, d32 = d16 * d16, d64 = d32 * d32;

  float* base = Ubuf + ((size_t)b * 64) * 4096 + (size_t)i * 64 + jq * 16 + j4 * 4;

  float4 S = {0.f, 0.f, 0.f, 0.f};
  float4 Un = *(const float4*)base;      // U of chunk 0
  for (int c = 0; c < 64; ++c) {
    float4 Uc = Un;
    if (c < 63) Un = *(const float4*)(base + (size_t)(c + 1) * 4096);
    *(float4*)(base + (size_t)c * 4096) = S;   // S_start(c)
    S.x = fmaf(d64, S.x, Uc.x);
    S.y = fmaf(d64, S.y, Uc.y);
    S.z = fmaf(d64, S.z, Uc.z);
    S.w = fmaf(d64, S.w, Uc.w);
  }
}

// ---------------------------------------------------------------------------
// Phase C: o[u,i] = d_i^{u+1} * sum_j S_start[i][j] q_u[j]  + so[u,i]
// Block per (b,chunk); same 16x16 x (4x4) tiling.
// ---------------------------------------------------------------------------
__global__ __launch_bounds__(256) void scan_chunk_c(
    const float* __restrict__ qkv, const float* __restrict__ decay,
    const float* __restrict__ Sbuf, float* __restrict__ so)
{
  __shared__ float Ss[64 * PAD];
  __shared__ float Qs[64 * PAD];
  __shared__ float l2d[64];

  const int tid = threadIdx.x;
  const int bc  = blockIdx.x;
  const int b   = bc >> 6;
  const int ch  = bc & 63;
  const int ti  = tid >> 4;
  const int tj  = tid & 15;

  // stage S_start (64x64) and Q chunk (64x64)
  #pragma unroll
  for (int it = 0; it < 4; ++it) {
    int idx = tid + it * 256;
    int row = idx >> 4, col4 = idx & 15;
    float4 s4 = *(const float4*)(Sbuf + (size_t)bc * 4096 + (size_t)row * 64 + col4 * 4);
    *ldsP(Ss, row, col4) = s4;
    float4 q4 = *(const float4*)(qkv + ((size_t)(b * Tt + ch * 64 + row)) * 192 + col4 * 4);
    *ldsP(Qs, row, col4) = q4;
  }
  if (tid < 64) {
    float d = 1.0f / (1.0f + expf(-decay[tid]));
    l2d[tid] = log2f(d);
  }
  __syncthreads();

  // acc[r][c]: u = ti*4+r, i = tj*4+c; inner j
  float acc[4][4] = {};
  #pragma unroll
  for (int j4 = 0; j4 < 16; ++j4) {
    float4 Q4[4], S4[4];
    #pragma unroll
    for (int r = 0; r < 4; ++r) Q4[r] = *ldsP(Qs, ti * 4 + r, j4);
    #pragma unroll
    for (int c = 0; c < 4; ++c) S4[c] = *ldsP(Ss, tj * 4 + c, j4);
    #pragma unroll
    for (int r = 0; r < 4; ++r)
      #pragma unroll
      for (int c = 0; c < 4; ++c) {
        acc[r][c] = fmaf(Q4[r].x, S4[c].x, acc[r][c]);
        acc[r][c] = fmaf(Q4[r].y, S4[c].y, acc[r][c]);
        acc[r][c] = fmaf(Q4[r].z, S4[c].z, acc[r][c]);
        acc[r][c] = fmaf(Q4[r].w, S4[c].w, acc[r][c]);
      }
  }

  #pragma unroll
  for (int r = 0; r < 4; ++r) {
    int u = ti * 4 + r;
    size_t row = (size_t)(b * Tt + ch * 64 + u);
    float4 prev = *(const float4*)(so + row * 64 + tj * 4);
    float e0 = exp2f((float)(u + 1) * l2d[tj * 4 + 0]);
    float e1 = exp2f((float)(u + 1) * l2d[tj * 4 + 1]);
    float e2 = exp2f((float)(u + 1) * l2d[tj * 4 + 2]);
    float e3 = exp2f((float)(u + 1) * l2d[tj * 4 + 3]);
    float4 o;
    o.x = fmaf(acc[r][0], e0, prev.x);
    o.y = fmaf(acc[r][1], e1, prev.y);
    o.z = fmaf(acc[r][2], e2, prev.z);
    o.w = fmaf(acc[r][3], e3, prev.w);
    *(float4*)(so + row * 64 + tj * 4) = o;
  }
}

// ---------------------------------------------------------------------------
// Kernel 3: out[M][1024] = x + scan_out[M][64] @ Wo^T + bo (unchanged)
// ---------------------------------------------------------------------------
__global__ __launch_bounds__(256) void out_gemm(
    const float* __restrict__ x, const float* __restrict__ so,
    const float* __restrict__ Wo, const float* __restrict__ bo,
    float* __restrict__ out)
{
  __shared__ float wsh[64 * 256];
  __shared__ float ssh[16 * 64];

  const int t   = threadIdx.x;
  const int cb  = blockIdx.x & 3;
  const int c0  = cb * 256;
  const int rb0 = (blockIdx.x >> 2) * 128;

  {
    const float* wrow = Wo + (size_t)(c0 + t) * 64;
    #pragma unroll
    for (int f = 0; f < 16; ++f) {
      float4 g = *(const float4*)(wrow + f * 4);
      wsh[(f * 4 + 0) * 256 + t] = g.x;
      wsh[(f * 4 + 1) * 256 + t] = g.y;
      wsh[(f * 4 + 2) * 256 + t] = g.z;
      wsh[(f * 4 + 3) * 256 + t] = g.w;
    }
  }

  const int tc = t & 63, tr = t >> 6;
  float4 bo4 = *(const float4*)(bo + c0 + tc * 4);
  __syncthreads();

  for (int rb = 0; rb < 8; ++rb) {
    __syncthreads();
    {
      float4 g = ((const float4*)(so + (size_t)(rb0 + rb * 16) * 64))[t];
      *(float4*)(&ssh[t * 4]) = g;
    }
    __syncthreads();

    float acc[4][4] = {};
    #pragma unroll
    for (int k = 0; k < 64; ++k) {
      float4 w4 = *(const float4*)(&wsh[k * 256 + tc * 4]);
      #pragma unroll
      for (int rr = 0; rr < 4; ++rr) {
        float sv = ssh[(tr * 4 + rr) * 64 + k];
        acc[rr][0] = fmaf(sv, w4.x, acc[rr][0]);
        acc[rr][1] = fmaf(sv, w4.y, acc[rr][1]);
        acc[rr][2] = fmaf(sv, w4.z, acc[rr][2]);
        acc[rr][3] = fmaf(sv, w4.w, acc[rr][3]);
      }
    }

    #pragma unroll
    for (int rr = 0; rr < 4; ++rr) {
      size_t m = (size_t)rb0 + rb * 16 + tr * 4 + rr;
      const float4 xv = *(const float4*)(x + m * 1024 + c0 + tc * 4);
      float4 o;
      o.x = xv.x + acc[rr][0] + bo4.x;
      o.y = xv.y + acc[rr][1] + bo4.y;
      o.z = xv.z + acc[rr][2] + bo4.z;
      o.w = xv.w + acc[rr][3] + bo4.w;
      *(float4*)(out + m * 1024 + c0 + tc * 4) = o;
    }
  }
}

// ---------------------------------------------------------------------------
extern "C" void kernel_launch(void* const* d_in, const int* in_sizes, int n_in,
                              void* d_out, int out_size, void* d_ws, size_t ws_size,
                              hipStream_t stream)
{
  const float* x   = (const float*)d_in[0];
  const float* Wq  = (const float*)d_in[1];
  const float* bq  = (const float*)d_in[2];
  const float* Wk  = (const float*)d_in[3];
  const float* bk  = (const float*)d_in[4];
  const float* Wv  = (const float*)d_in[5];
  const float* bv  = (const float*)d_in[6];
  const float* dec = (const float*)d_in[7];
  const float* Wo  = (const float*)d_in[8];
  const float* bo  = (const float*)d_in[9];
  float* out = (float*)d_out;

  float* qkv  = (float*)d_ws;                       // [M][192] = 25.2 MB
  float* so   = qkv + (size_t)Mm * 192;             // [M][64]  =  8.4 MB
  float* Ubuf = so + (size_t)Mm * 64;               // [8*64][64][64] = 8.4 MB (U, then S_start)

  qkv_gemm<<<Mm / 64, 256, 0, stream>>>(x, Wq, bq, Wk, bk, Wv, bv, qkv);
  scan_chunk_a<<<512, 256, 0, stream>>>(qkv, dec, Ubuf, so);
  scan_state<<<32, 256, 0, stream>>>(dec, Ubuf);
  scan_chunk_c<<<512, 256, 0, stream>>>(qkv, dec, Ubuf, so);
  out_gemm<<<(Mm / 128) * 4, 256, 0, stream>>>(x, so, Wo, bo, out);
}

// Round 6
// 431.120 us; speedup vs baseline: 3.0722x; 1.1692x over previous
//
#include <hip/hip_runtime.h>
#include <cstdint>
#include <cstddef>
#include <cmath>

#define Bb 8
#define Tt 4096
#define Dd 1024
#define DS 64
#define Mm (Bb*Tt)   // 32768
#define PAD 68       // floats per LDS row (16B-aligned rows: 68*4=272B)

typedef __bf16 bf16x8 __attribute__((ext_vector_type(8)));
typedef __bf16 bf16x4v __attribute__((ext_vector_type(4)));
typedef float f32x4 __attribute__((ext_vector_type(4)));

// float4 pointer into a [64][PAD] LDS tile at logical (row, col4),
// XOR-swizzled so column-slice reads spread across banks.
__device__ __forceinline__ float4* ldsP(float* buf, int row, int col4) {
  return (float4*)(buf + row * PAD + (((col4) ^ ((row >> 3) & 7)) << 2));
}

// ---------------------------------------------------------------------------
// convert_w: Wq|Wk|Wv (stacked [192][1024]) and Wo ([1024][64]) -> bf16
// ---------------------------------------------------------------------------
__global__ __launch_bounds__(256) void convert_w(
    const float* __restrict__ Wq, const float* __restrict__ Wk,
    const float* __restrict__ Wv, const float* __restrict__ Wo,
    __bf16* __restrict__ Wqkvb, __bf16* __restrict__ Wob)
{
  int idx = blockIdx.x * 256 + threadIdx.x;
  if (idx < 196608) {
    float v = (idx < 65536) ? Wq[idx]
            : (idx < 131072) ? Wk[idx - 65536] : Wv[idx - 131072];
    Wqkvb[idx] = (__bf16)v;
  }
  if (idx < 65536) Wob[idx] = (__bf16)Wo[idx];
}

// ---------------------------------------------------------------------------
// Kernel 1: QKV projection via MFMA. qkv[M][192] = X[M][1024] @ W^T + bias.
// No LDS: per-lane fragment-shaped global loads; x converted fp32->bf16
// in-register. Block = 256 thr = 4 waves; wave w owns rows m0..m0+64,
// cols w*48..w*48+48 (4 m-frags x 3 n-frags of 16x16).
// A frag layout: row = l&15, k = (l>>4)*8 + j.  B frag: col = l&15, same k.
// D frag: col = l&15, row = (l>>4)*4 + reg.   [verified m89/m91]
// ---------------------------------------------------------------------------
__global__ __launch_bounds__(256) void qkv_mfma(
    const float* __restrict__ x, const __bf16* __restrict__ Wb,
    const float* __restrict__ bq, const float* __restrict__ bk,
    const float* __restrict__ bv, float* __restrict__ qkv)
{
  const int w  = threadIdx.x >> 6;
  const int l  = threadIdx.x & 63;
  const int m0 = blockIdx.x * 64;
  const int c0 = w * 48;
  const int lr = l & 15;
  const int lk = l >> 4;

  f32x4 acc[4][3] = {};

  const float*  ax = x  + (size_t)(m0 + lr) * 1024 + lk * 8;
  const __bf16* bw = Wb + (size_t)(c0 + lr) * 1024 + lk * 8;

  for (int k0 = 0; k0 < 1024; k0 += 32) {
    bf16x8 a[4], b[3];
    #pragma unroll
    for (int mf = 0; mf < 4; ++mf) {
      const float* p = ax + (size_t)mf * 16 * 1024 + k0;
      float4 f0 = *(const float4*)p;
      float4 f1 = *(const float4*)(p + 4);
      bf16x8 t;
      t[0] = (__bf16)f0.x; t[1] = (__bf16)f0.y;
      t[2] = (__bf16)f0.z; t[3] = (__bf16)f0.w;
      t[4] = (__bf16)f1.x; t[5] = (__bf16)f1.y;
      t[6] = (__bf16)f1.z; t[7] = (__bf16)f1.w;
      a[mf] = t;
    }
    #pragma unroll
    for (int nf = 0; nf < 3; ++nf)
      b[nf] = *(const bf16x8*)(bw + (size_t)nf * 16 * 1024 + k0);
    #pragma unroll
    for (int mf = 0; mf < 4; ++mf)
      #pragma unroll
      for (int nf = 0; nf < 3; ++nf)
        acc[mf][nf] = __builtin_amdgcn_mfma_f32_16x16x32_bf16(
            a[mf], b[nf], acc[mf][nf], 0, 0, 0);
  }

  float bias[3];
  #pragma unroll
  for (int nf = 0; nf < 3; ++nf) {
    int j = c0 + nf * 16 + lr;
    bias[nf] = (j < 64) ? bq[j] : (j < 128) ? bk[j - 64] : bv[j - 128];
  }

  #pragma unroll
  for (int mf = 0; mf < 4; ++mf)
    #pragma unroll
    for (int nf = 0; nf < 3; ++nf) {
      int j = c0 + nf * 16 + lr;
      #pragma unroll
      for (int r = 0; r < 4; ++r) {
        int m = m0 + mf * 16 + lk * 4 + r;
        qkv[(size_t)m * 192 + j] = acc[mf][nf][r] + bias[nf];
      }
    }
}

// ---------------------------------------------------------------------------
// Phase A: per (b,chunk): G = causal(Q K^T) (stored transposed GT[s][u]),
//   Vt[s,i] = v_s[i] * d_i^{-s},
//   U[i,j]  = d_i^63 * sum_s Vt[s,i] K[s,j]      -> Ubuf
//   intra[u,i] = d_i^u * sum_s GT[s,u] Vt[s,i]   -> so (phase C adds to it)
// ---------------------------------------------------------------------------
__global__ __launch_bounds__(256) void scan_chunk_a(
    const float* __restrict__ qkv, const float* __restrict__ decay,
    float* __restrict__ Ubuf, float* __restrict__ so)
{
  __shared__ float Qs[64 * PAD];   // later overwritten with GT
  __shared__ float Ks[64 * PAD];
  __shared__ float Vs[64 * PAD];   // scaled to Vt in place
  __shared__ float l2d[64];

  const int tid = threadIdx.x;
  const int bc  = blockIdx.x;          // b*64 + ch
  const int b   = bc >> 6;
  const int ch  = bc & 63;
  const int ti  = tid >> 4;
  const int tj  = tid & 15;

  const float* base = qkv + ((size_t)(b * Tt + ch * 64)) * 192;

  #pragma unroll
  for (int it = 0; it < 12; ++it) {
    int idx = tid + it * 256;
    int row = idx / 48, f = idx % 48;
    float4 g = *(const float4*)(base + (size_t)row * 192 + f * 4);
    float4* dst;
    if (f < 16)      dst = ldsP(Qs, row, f);
    else if (f < 32) dst = ldsP(Ks, row, f - 16);
    else             dst = ldsP(Vs, row, f - 32);
    *dst = g;
  }
  if (tid < 64) {
    float d = 1.0f / (1.0f + expf(-decay[tid]));
    l2d[tid] = log2f(d);
  }
  __syncthreads();

  {
    int s = tid >> 2;
    #pragma unroll
    for (int g4 = 0; g4 < 4; ++g4) {
      int col4 = (tid & 3) * 4 + g4;
      float4* p = ldsP(Vs, s, col4);
      float4 v = *p;
      float e0 = exp2f(-(float)s * l2d[col4 * 4 + 0]);
      float e1 = exp2f(-(float)s * l2d[col4 * 4 + 1]);
      float e2 = exp2f(-(float)s * l2d[col4 * 4 + 2]);
      float e3 = exp2f(-(float)s * l2d[col4 * 4 + 3]);
      v.x *= e0; v.y *= e1; v.z *= e2; v.w *= e3;
      *p = v;
    }
  }

  float gval[4][4] = {};
  #pragma unroll
  for (int kk4 = 0; kk4 < 16; ++kk4) {
    float4 K4[4], Q4[4];
    #pragma unroll
    for (int r = 0; r < 4; ++r) K4[r] = *ldsP(Ks, ti * 4 + r, kk4);
    #pragma unroll
    for (int c = 0; c < 4; ++c) Q4[c] = *ldsP(Qs, tj * 4 + c, kk4);
    #pragma unroll
    for (int r = 0; r < 4; ++r)
      #pragma unroll
      for (int c = 0; c < 4; ++c) {
        gval[r][c] = fmaf(K4[r].x, Q4[c].x, gval[r][c]);
        gval[r][c] = fmaf(K4[r].y, Q4[c].y, gval[r][c]);
        gval[r][c] = fmaf(K4[r].z, Q4[c].z, gval[r][c]);
        gval[r][c] = fmaf(K4[r].w, Q4[c].w, gval[r][c]);
      }
  }
  #pragma unroll
  for (int r = 0; r < 4; ++r)
    #pragma unroll
    for (int c = 0; c < 4; ++c)
      if (ti * 4 + r > tj * 4 + c) gval[r][c] = 0.0f;

  __syncthreads();

  #pragma unroll
  for (int r = 0; r < 4; ++r) {
    float4 g4 = {gval[r][0], gval[r][1], gval[r][2], gval[r][3]};
    *ldsP(Qs, ti * 4 + r, tj) = g4;
  }
  __syncthreads();

  float uacc[4][4] = {};
  float oacc[4][4] = {};
  for (int s = 0; s < 64; ++s) {
    float4 Vti = *ldsP(Vs, s, ti);
    float4 Ktj = *ldsP(Ks, s, tj);
    float4 Gti = *ldsP(Qs, s, ti);
    float4 Vtj = *ldsP(Vs, s, tj);
    const float vi[4] = {Vti.x, Vti.y, Vti.z, Vti.w};
    const float kj[4] = {Ktj.x, Ktj.y, Ktj.z, Ktj.w};
    const float gu[4] = {Gti.x, Gti.y, Gti.z, Gti.w};
    const float vj[4] = {Vtj.x, Vtj.y, Vtj.z, Vtj.w};
    #pragma unroll
    for (int r = 0; r < 4; ++r)
      #pragma unroll
      for (int c = 0; c < 4; ++c) {
        uacc[r][c] = fmaf(vi[r], kj[c], uacc[r][c]);
        oacc[r][c] = fmaf(gu[r], vj[c], oacc[r][c]);
      }
  }

  #pragma unroll
  for (int r = 0; r < 4; ++r) {
    int i = ti * 4 + r;
    float d63 = exp2f(63.0f * l2d[i]);
    float4 o = {uacc[r][0] * d63, uacc[r][1] * d63,
                uacc[r][2] * d63, uacc[r][3] * d63};
    *(float4*)(Ubuf + ((size_t)bc * 64 + i) * 64 + tj * 4) = o;
  }
  #pragma unroll
  for (int r = 0; r < 4; ++r) {
    int u = ti * 4 + r;
    float e0 = exp2f((float)u * l2d[tj * 4 + 0]);
    float e1 = exp2f((float)u * l2d[tj * 4 + 1]);
    float e2 = exp2f((float)u * l2d[tj * 4 + 2]);
    float e3 = exp2f((float)u * l2d[tj * 4 + 3]);
    float4 o = {oacc[r][0] * e0, oacc[r][1] * e1,
                oacc[r][2] * e2, oacc[r][3] * e3};
    *(float4*)(so + ((size_t)(b * Tt + ch * 64 + u)) * 64 + tj * 4) = o;
  }
}

// ---------------------------------------------------------------------------
// Phase B: sequential over 64 chunks; in-place U -> S_start.
// 4-deep static-indexed prefetch to hide HBM latency (was 1-deep).
// ---------------------------------------------------------------------------
__global__ __launch_bounds__(256) void scan_state(
    const float* __restrict__ decay, float* __restrict__ Ubuf)
{
  const int b  = blockIdx.x >> 2;
  const int jq = blockIdx.x & 3;
  const int i  = threadIdx.x >> 2;
  const int j4 = threadIdx.x & 3;

  float d = 1.0f / (1.0f + expf(-decay[i]));
  float d2 = d * d, d4 = d2 * d2, d8 = d4 * d4;
  float d16 = d8 * d8, d32 = d16 * d16, d64 = d32 * d32;

  float* base = Ubuf + ((size_t)b * 64) * 4096 + (size_t)i * 64 + jq * 16 + j4 * 4;

  float4 S = {0.f, 0.f, 0.f, 0.f};
  float4 u0 = *(const float4*)(base + 0 * 4096);
  float4 u1 = *(const float4*)(base + 1 * 4096);
  float4 u2 = *(const float4*)(base + 2 * 4096);
  float4 u3 = *(const float4*)(base + 3 * 4096);

  for (int c = 0; c < 64; c += 4) {
    float4 n0 = u0, n1 = u1, n2 = u2, n3 = u3;
    if (c + 4 < 64) {
      n0 = *(const float4*)(base + (size_t)(c + 4) * 4096);
      n1 = *(const float4*)(base + (size_t)(c + 5) * 4096);
      n2 = *(const float4*)(base + (size_t)(c + 6) * 4096);
      n3 = *(const float4*)(base + (size_t)(c + 7) * 4096);
    }
    *(float4*)(base + (size_t)(c + 0) * 4096) = S;
    S.x = fmaf(d64, S.x, u0.x); S.y = fmaf(d64, S.y, u0.y);
    S.z = fmaf(d64, S.z, u0.z); S.w = fmaf(d64, S.w, u0.w);
    *(float4*)(base + (size_t)(c + 1) * 4096) = S;
    S.x = fmaf(d64, S.x, u1.x); S.y = fmaf(d64, S.y, u1.y);
    S.z = fmaf(d64, S.z, u1.z); S.w = fmaf(d64, S.w, u1.w);
    *(float4*)(base + (size_t)(c + 2) * 4096) = S;
    S.x = fmaf(d64, S.x, u2.x); S.y = fmaf(d64, S.y, u2.y);
    S.z = fmaf(d64, S.z, u2.z); S.w = fmaf(d64, S.w, u2.w);
    *(float4*)(base + (size_t)(c + 3) * 4096) = S;
    S.x = fmaf(d64, S.x, u3.x); S.y = fmaf(d64, S.y, u3.y);
    S.z = fmaf(d64, S.z, u3.z); S.w = fmaf(d64, S.w, u3.w);
    u0 = n0; u1 = n1; u2 = n2; u3 = n3;
  }
}

// ---------------------------------------------------------------------------
// Phase C: o[u,i] = d_i^{u+1} * sum_j S_start[i][j] q_u[j]  + so[u,i]
// Writes FINAL scan output as bf16 (sob) for the MFMA out-projection.
// ---------------------------------------------------------------------------
__global__ __launch_bounds__(256) void scan_chunk_c(
    const float* __restrict__ qkv, const float* __restrict__ decay,
    const float* __restrict__ Sbuf, const float* __restrict__ so,
    __bf16* __restrict__ sob)
{
  __shared__ float Ss[64 * PAD];
  __shared__ float Qs[64 * PAD];
  __shared__ float l2d[64];

  const int tid = threadIdx.x;
  const int bc  = blockIdx.x;
  const int b   = bc >> 6;
  const int ch  = bc & 63;
  const int ti  = tid >> 4;
  const int tj  = tid & 15;

  #pragma unroll
  for (int it = 0; it < 4; ++it) {
    int idx = tid + it * 256;
    int row = idx >> 4, col4 = idx & 15;
    float4 s4 = *(const float4*)(Sbuf + (size_t)bc * 4096 + (size_t)row * 64 + col4 * 4);
    *ldsP(Ss, row, col4) = s4;
    float4 q4 = *(const float4*)(qkv + ((size_t)(b * Tt + ch * 64 + row)) * 192 + col4 * 4);
    *ldsP(Qs, row, col4) = q4;
  }
  if (tid < 64) {
    float d = 1.0f / (1.0f + expf(-decay[tid]));
    l2d[tid] = log2f(d);
  }
  __syncthreads();

  float acc[4][4] = {};
  #pragma unroll
  for (int j4 = 0; j4 < 16; ++j4) {
    float4 Q4[4], S4[4];
    #pragma unroll
    for (int r = 0; r < 4; ++r) Q4[r] = *ldsP(Qs, ti * 4 + r, j4);
    #pragma unroll
    for (int c = 0; c < 4; ++c) S4[c] = *ldsP(Ss, tj * 4 + c, j4);
    #pragma unroll
    for (int r = 0; r < 4; ++r)
      #pragma unroll
      for (int c = 0; c < 4; ++c) {
        acc[r][c] = fmaf(Q4[r].x, S4[c].x, acc[r][c]);
        acc[r][c] = fmaf(Q4[r].y, S4[c].y, acc[r][c]);
        acc[r][c] = fmaf(Q4[r].z, S4[c].z, acc[r][c]);
        acc[r][c] = fmaf(Q4[r].w, S4[c].w, acc[r][c]);
      }
  }

  #pragma unroll
  for (int r = 0; r < 4; ++r) {
    int u = ti * 4 + r;
    size_t row = (size_t)(b * Tt + ch * 64 + u);
    float4 prev = *(const float4*)(so + row * 64 + tj * 4);
    float e0 = exp2f((float)(u + 1) * l2d[tj * 4 + 0]);
    float e1 = exp2f((float)(u + 1) * l2d[tj * 4 + 1]);
    float e2 = exp2f((float)(u + 1) * l2d[tj * 4 + 2]);
    float e3 = exp2f((float)(u + 1) * l2d[tj * 4 + 3]);
    bf16x4v ov;
    ov[0] = (__bf16)fmaf(acc[r][0], e0, prev.x);
    ov[1] = (__bf16)fmaf(acc[r][1], e1, prev.y);
    ov[2] = (__bf16)fmaf(acc[r][2], e2, prev.z);
    ov[3] = (__bf16)fmaf(acc[r][3], e3, prev.w);
    *(bf16x4v*)(sob + row * 64 + tj * 4) = ov;
  }
}

// ---------------------------------------------------------------------------
// Kernel 3: out[M][1024] = x + sob[M][64] @ Wo^T + bo via MFMA, no LDS.
// Block = 256 thr = 4 waves (2x2); block tile 128x128; wave tile 64x64
// (4 m-frags x 4 n-frags, K=64 = 2 k-substeps).
// ---------------------------------------------------------------------------
__global__ __launch_bounds__(256) void out_mfma(
    const float* __restrict__ x, const __bf16* __restrict__ sob,
    const __bf16* __restrict__ Wob, const float* __restrict__ bo,
    float* __restrict__ out)
{
  const int bid = blockIdx.x;
  const int rb  = bid >> 3;
  const int cb  = bid & 7;
  const int w   = threadIdx.x >> 6;
  const int l   = threadIdx.x & 63;
  const int wr  = w >> 1;
  const int wc  = w & 1;
  const int m0  = rb * 128 + wr * 64;
  const int c0  = cb * 128 + wc * 64;
  const int lr  = l & 15;
  const int lk  = l >> 4;

  f32x4 acc[4][4] = {};

  const __bf16* ap = sob + (size_t)(m0 + lr) * 64 + lk * 8;
  const __bf16* bp = Wob + (size_t)(c0 + lr) * 64 + lk * 8;

  #pragma unroll
  for (int ks = 0; ks < 2; ++ks) {
    bf16x8 a[4], b[4];
    #pragma unroll
    for (int mf = 0; mf < 4; ++mf)
      a[mf] = *(const bf16x8*)(ap + (size_t)mf * 16 * 64 + ks * 32);
    #pragma unroll
    for (int nf = 0; nf < 4; ++nf)
      b[nf] = *(const bf16x8*)(bp + (size_t)nf * 16 * 64 + ks * 32);
    #pragma unroll
    for (int mf = 0; mf < 4; ++mf)
      #pragma unroll
      for (int nf = 0; nf < 4; ++nf)
        acc[mf][nf] = __builtin_amdgcn_mfma_f32_16x16x32_bf16(
            a[mf], b[nf], acc[mf][nf], 0, 0, 0);
  }

  #pragma unroll
  for (int nf = 0; nf < 4; ++nf) {
    int j = c0 + nf * 16 + lr;
    float bj = bo[j];
    #pragma unroll
    for (int mf = 0; mf < 4; ++mf) {
      #pragma unroll
      for (int r = 0; r < 4; ++r) {
        size_t m = (size_t)m0 + mf * 16 + lk * 4 + r;
        out[m * 1024 + j] = x[m * 1024 + j] + acc[mf][nf][r] + bj;
      }
    }
  }
}

// ---------------------------------------------------------------------------
extern "C" void kernel_launch(void* const* d_in, const int* in_sizes, int n_in,
                              void* d_out, int out_size, void* d_ws, size_t ws_size,
                              hipStream_t stream)
{
  const float* x   = (const float*)d_in[0];
  const float* Wq  = (const float*)d_in[1];
  const float* bq  = (const float*)d_in[2];
  const float* Wk  = (const float*)d_in[3];
  const float* bk  = (const float*)d_in[4];
  const float* Wv  = (const float*)d_in[5];
  const float* bv  = (const float*)d_in[6];
  const float* dec = (const float*)d_in[7];
  const float* Wo  = (const float*)d_in[8];
  const float* bo  = (const float*)d_in[9];
  float* out = (float*)d_out;

  float*  qkv   = (float*)d_ws;                    // [M][192] fp32 = 25.2 MB
  float*  so    = qkv + (size_t)Mm * 192;          // [M][64]  fp32 =  8.4 MB
  float*  Ubuf  = so + (size_t)Mm * 64;            // [512][64][64] =  8.4 MB
  __bf16* sob   = (__bf16*)(Ubuf + (size_t)512 * 4096);  // [M][64] bf16 = 4.2 MB
  __bf16* Wqkvb = sob + (size_t)Mm * 64;           // [192][1024]
  __bf16* Wob   = Wqkvb + (size_t)192 * 1024;      // [1024][64]

  convert_w<<<768, 256, 0, stream>>>(Wq, Wk, Wv, Wo, Wqkvb, Wob);
  qkv_mfma<<<Mm / 64, 256, 0, stream>>>(x, Wqkvb, bq, bk, bv, qkv);
  scan_chunk_a<<<512, 256, 0, stream>>>(qkv, dec, Ubuf, so);
  scan_state<<<32, 256, 0, stream>>>(dec, Ubuf);
  scan_chunk_c<<<512, 256, 0, stream>>>(qkv, dec, Ubuf, so, sob);
  out_mfma<<<2048, 256, 0, stream>>>(x, sob, Wob, bo, out);
}

// Round 7
// 388.742 us; speedup vs baseline: 3.4071x; 1.1090x over previous
//
#include <hip/hip_runtime.h>
#include <cstdint>
#include <cstddef>
#include <cmath>

#define Bb 8
#define Tt 4096
#define Dd 1024
#define DS 64
#define Mm (Bb*Tt)   // 32768
#define PAD 68       // floats per LDS row (fp32 scan tiles)

typedef __bf16 bf16x8 __attribute__((ext_vector_type(8)));
typedef __bf16 bf16x4v __attribute__((ext_vector_type(4)));
typedef float f32x4 __attribute__((ext_vector_type(4)));

// float4 pointer into a [64][PAD] fp32 LDS tile, XOR-swizzled (scan kernels)
__device__ __forceinline__ float4* ldsP(float* buf, int row, int col4) {
  return (float4*)(buf + row * PAD + (((col4) ^ ((row >> 3) & 7)) << 2));
}

// ---------------------------------------------------------------------------
// convert_w: Wq|Wk|Wv (stacked [192][1024]) and Wo ([1024][64]) -> bf16
// ---------------------------------------------------------------------------
__global__ __launch_bounds__(256) void convert_w(
    const float* __restrict__ Wq, const float* __restrict__ Wk,
    const float* __restrict__ Wv, const float* __restrict__ Wo,
    __bf16* __restrict__ Wqkvb, __bf16* __restrict__ Wob)
{
  int idx = blockIdx.x * 256 + threadIdx.x;
  if (idx < 196608) {
    float v = (idx < 65536) ? Wq[idx]
            : (idx < 131072) ? Wk[idx - 65536] : Wv[idx - 131072];
    Wqkvb[idx] = (__bf16)v;
  }
  if (idx < 65536) Wob[idx] = (__bf16)Wo[idx];
}

// ---------------------------------------------------------------------------
// Kernel 1: QKV projection via MFMA, operand-swapped (A=W rows j, B=x rows m)
// so D reg-index runs along j -> float4 stores. x tile staged+converted ONCE
// per block in LDS (bf16, XOR-swizzled rows of 128B).
// Block 256 thr = 4 waves; wave w: cols c0=w*48 (3 j-frags), rows m0..m0+63
// (4 m-frags). K-step 64 (2 sub-steps of 32).
// ---------------------------------------------------------------------------
__global__ __launch_bounds__(256) void qkv_mfma(
    const float* __restrict__ x, const __bf16* __restrict__ Wb,
    const float* __restrict__ bq, const float* __restrict__ bk,
    const float* __restrict__ bv, float* __restrict__ qkv)
{
  __shared__ __bf16 xs[64 * 64];   // [row m][k] bf16, 8KB, swizzled

  const int tid = threadIdx.x;
  const int w   = tid >> 6;
  const int l   = tid & 63;
  const int m0  = blockIdx.x * 64;
  const int c0  = w * 48;
  const int lr  = l & 15;
  const int lk  = l >> 4;

  // staging role: row srow (0..63), k-group sk (16 floats)
  const int srow = tid & 63;
  const int sk   = (tid >> 6) * 16;
  const float* xsrc = x + (size_t)(m0 + srow) * 1024 + sk;
  // LDS byte offsets for the two 16B chunks this thread writes
  const int wb0 = srow * 128 + ((sk * 2 + 0)  ^ ((srow & 7) << 4));
  const int wb1 = srow * 128 + ((sk * 2 + 16) ^ ((srow & 7) << 4));

  f32x4 acc[3][4] = {};   // [jf][mf]

  float4 f0 = *(const float4*)(xsrc + 0);
  float4 f1 = *(const float4*)(xsrc + 4);
  float4 f2 = *(const float4*)(xsrc + 8);
  float4 f3 = *(const float4*)(xsrc + 12);

  for (int k0 = 0; k0 < 1024; k0 += 64) {
    bf16x8 h0, h1;
    h0[0] = (__bf16)f0.x; h0[1] = (__bf16)f0.y; h0[2] = (__bf16)f0.z; h0[3] = (__bf16)f0.w;
    h0[4] = (__bf16)f1.x; h0[5] = (__bf16)f1.y; h0[6] = (__bf16)f1.z; h0[7] = (__bf16)f1.w;
    h1[0] = (__bf16)f2.x; h1[1] = (__bf16)f2.y; h1[2] = (__bf16)f2.z; h1[3] = (__bf16)f2.w;
    h1[4] = (__bf16)f3.x; h1[5] = (__bf16)f3.y; h1[6] = (__bf16)f3.z; h1[7] = (__bf16)f3.w;

    __syncthreads();   // previous iter's LDS reads complete
    *(bf16x8*)((char*)xs + wb0) = h0;
    *(bf16x8*)((char*)xs + wb1) = h1;
    __syncthreads();   // writes visible

    if (k0 + 64 < 1024) {
      f0 = *(const float4*)(xsrc + k0 + 64);
      f1 = *(const float4*)(xsrc + k0 + 68);
      f2 = *(const float4*)(xsrc + k0 + 72);
      f3 = *(const float4*)(xsrc + k0 + 76);
    }

    #pragma unroll
    for (int ks = 0; ks < 2; ++ks) {
      bf16x8 wf[3], xf[4];
      #pragma unroll
      for (int jf = 0; jf < 3; ++jf)
        wf[jf] = *(const bf16x8*)(Wb + (size_t)(c0 + jf * 16 + lr) * 1024
                                     + k0 + ks * 32 + lk * 8);
      #pragma unroll
      for (int mf = 0; mf < 4; ++mf) {
        int row = mf * 16 + lr;
        int boff = row * 128 + ((ks * 64 + lk * 16) ^ ((row & 7) << 4));
        xf[mf] = *(const bf16x8*)((const char*)xs + boff);
      }
      #pragma unroll
      for (int jf = 0; jf < 3; ++jf)
        #pragma unroll
        for (int mf = 0; mf < 4; ++mf)
          acc[jf][mf] = __builtin_amdgcn_mfma_f32_16x16x32_bf16(
              wf[jf], xf[mf], acc[jf][mf], 0, 0, 0);
    }
  }

  // epilogue: j = c0 + jf*16 + lk*4 + r (contiguous), m = m0 + mf*16 + lr
  #pragma unroll
  for (int jf = 0; jf < 3; ++jf) {
    int j0 = c0 + jf * 16 + lk * 4;
    const float* bsrc = (j0 < 64) ? (bq + j0)
                      : (j0 < 128) ? (bk + j0 - 64) : (bv + j0 - 128);
    float4 b4 = *(const float4*)bsrc;
    #pragma unroll
    for (int mf = 0; mf < 4; ++mf) {
      int m = m0 + mf * 16 + lr;
      float4 o;
      o.x = acc[jf][mf][0] + b4.x;
      o.y = acc[jf][mf][1] + b4.y;
      o.z = acc[jf][mf][2] + b4.z;
      o.w = acc[jf][mf][3] + b4.w;
      *(float4*)(qkv + (size_t)m * 192 + j0) = o;
    }
  }
}

// ---------------------------------------------------------------------------
// Phase A: per (b,chunk): G = causal(Q K^T) (stored transposed GT[s][u]),
//   Vt[s,i] = v_s[i] * d_i^{-s},
//   U[i,j]  = d_i^63 * sum_s Vt[s,i] K[s,j]      -> Ubuf
//   intra[u,i] = d_i^u * sum_s GT[s,u] Vt[s,i]   -> so (phase C adds to it)
// ---------------------------------------------------------------------------
__global__ __launch_bounds__(256) void scan_chunk_a(
    const float* __restrict__ qkv, const float* __restrict__ decay,
    float* __restrict__ Ubuf, float* __restrict__ so)
{
  __shared__ float Qs[64 * PAD];   // later overwritten with GT
  __shared__ float Ks[64 * PAD];
  __shared__ float Vs[64 * PAD];   // scaled to Vt in place
  __shared__ float l2d[64];

  const int tid = threadIdx.x;
  const int bc  = blockIdx.x;          // b*64 + ch
  const int b   = bc >> 6;
  const int ch  = bc & 63;
  const int ti  = tid >> 4;
  const int tj  = tid & 15;

  const float* base = qkv + ((size_t)(b * Tt + ch * 64)) * 192;

  #pragma unroll
  for (int it = 0; it < 12; ++it) {
    int idx = tid + it * 256;
    int row = idx / 48, f = idx % 48;
    float4 g = *(const float4*)(base + (size_t)row * 192 + f * 4);
    float4* dst;
    if (f < 16)      dst = ldsP(Qs, row, f);
    else if (f < 32) dst = ldsP(Ks, row, f - 16);
    else             dst = ldsP(Vs, row, f - 32);
    *dst = g;
  }
  if (tid < 64) {
    float d = 1.0f / (1.0f + expf(-decay[tid]));
    l2d[tid] = log2f(d);
  }
  __syncthreads();

  {
    int s = tid >> 2;
    #pragma unroll
    for (int g4 = 0; g4 < 4; ++g4) {
      int col4 = (tid & 3) * 4 + g4;
      float4* p = ldsP(Vs, s, col4);
      float4 v = *p;
      float e0 = exp2f(-(float)s * l2d[col4 * 4 + 0]);
      float e1 = exp2f(-(float)s * l2d[col4 * 4 + 1]);
      float e2 = exp2f(-(float)s * l2d[col4 * 4 + 2]);
      float e3 = exp2f(-(float)s * l2d[col4 * 4 + 3]);
      v.x *= e0; v.y *= e1; v.z *= e2; v.w *= e3;
      *p = v;
    }
  }

  float gval[4][4] = {};
  #pragma unroll
  for (int kk4 = 0; kk4 < 16; ++kk4) {
    float4 K4[4], Q4[4];
    #pragma unroll
    for (int r = 0; r < 4; ++r) K4[r] = *ldsP(Ks, ti * 4 + r, kk4);
    #pragma unroll
    for (int c = 0; c < 4; ++c) Q4[c] = *ldsP(Qs, tj * 4 + c, kk4);
    #pragma unroll
    for (int r = 0; r < 4; ++r)
      #pragma unroll
      for (int c = 0; c < 4; ++c) {
        gval[r][c] = fmaf(K4[r].x, Q4[c].x, gval[r][c]);
        gval[r][c] = fmaf(K4[r].y, Q4[c].y, gval[r][c]);
        gval[r][c] = fmaf(K4[r].z, Q4[c].z, gval[r][c]);
        gval[r][c] = fmaf(K4[r].w, Q4[c].w, gval[r][c]);
      }
  }
  #pragma unroll
  for (int r = 0; r < 4; ++r)
    #pragma unroll
    for (int c = 0; c < 4; ++c)
      if (ti * 4 + r > tj * 4 + c) gval[r][c] = 0.0f;

  __syncthreads();

  #pragma unroll
  for (int r = 0; r < 4; ++r) {
    float4 g4 = {gval[r][0], gval[r][1], gval[r][2], gval[r][3]};
    *ldsP(Qs, ti * 4 + r, tj) = g4;
  }
  __syncthreads();

  float uacc[4][4] = {};
  float oacc[4][4] = {};
  for (int s = 0; s < 64; ++s) {
    float4 Vti = *ldsP(Vs, s, ti);
    float4 Ktj = *ldsP(Ks, s, tj);
    float4 Gti = *ldsP(Qs, s, ti);
    float4 Vtj = *ldsP(Vs, s, tj);
    const float vi[4] = {Vti.x, Vti.y, Vti.z, Vti.w};
    const float kj[4] = {Ktj.x, Ktj.y, Ktj.z, Ktj.w};
    const float gu[4] = {Gti.x, Gti.y, Gti.z, Gti.w};
    const float vj[4] = {Vtj.x, Vtj.y, Vtj.z, Vtj.w};
    #pragma unroll
    for (int r = 0; r < 4; ++r)
      #pragma unroll
      for (int c = 0; c < 4; ++c) {
        uacc[r][c] = fmaf(vi[r], kj[c], uacc[r][c]);
        oacc[r][c] = fmaf(gu[r], vj[c], oacc[r][c]);
      }
  }

  #pragma unroll
  for (int r = 0; r < 4; ++r) {
    int i = ti * 4 + r;
    float d63 = exp2f(63.0f * l2d[i]);
    float4 o = {uacc[r][0] * d63, uacc[r][1] * d63,
                uacc[r][2] * d63, uacc[r][3] * d63};
    *(float4*)(Ubuf + ((size_t)bc * 64 + i) * 64 + tj * 4) = o;
  }
  #pragma unroll
  for (int r = 0; r < 4; ++r) {
    int u = ti * 4 + r;
    float e0 = exp2f((float)u * l2d[tj * 4 + 0]);
    float e1 = exp2f((float)u * l2d[tj * 4 + 1]);
    float e2 = exp2f((float)u * l2d[tj * 4 + 2]);
    float e3 = exp2f((float)u * l2d[tj * 4 + 3]);
    float4 o = {oacc[r][0] * e0, oacc[r][1] * e1,
                oacc[r][2] * e2, oacc[r][3] * e3};
    *(float4*)(so + ((size_t)(b * Tt + ch * 64 + u)) * 64 + tj * 4) = o;
  }
}

// ---------------------------------------------------------------------------
// Phase B: sequential over 64 chunks; in-place U -> S_start. 4-deep prefetch.
// ---------------------------------------------------------------------------
__global__ __launch_bounds__(256) void scan_state(
    const float* __restrict__ decay, float* __restrict__ Ubuf)
{
  const int b  = blockIdx.x >> 2;
  const int jq = blockIdx.x & 3;
  const int i  = threadIdx.x >> 2;
  const int j4 = threadIdx.x & 3;

  float d = 1.0f / (1.0f + expf(-decay[i]));
  float d2 = d * d, d4 = d2 * d2, d8 = d4 * d4;
  float d16 = d8 * d8, d32 = d16 * d16, d64 = d32 * d32;

  float* base = Ubuf + ((size_t)b * 64) * 4096 + (size_t)i * 64 + jq * 16 + j4 * 4;

  float4 S = {0.f, 0.f, 0.f, 0.f};
  float4 u0 = *(const float4*)(base + 0 * 4096);
  float4 u1 = *(const float4*)(base + 1 * 4096);
  float4 u2 = *(const float4*)(base + 2 * 4096);
  float4 u3 = *(const float4*)(base + 3 * 4096);

  for (int c = 0; c < 64; c += 4) {
    float4 n0 = u0, n1 = u1, n2 = u2, n3 = u3;
    if (c + 4 < 64) {
      n0 = *(const float4*)(base + (size_t)(c + 4) * 4096);
      n1 = *(const float4*)(base + (size_t)(c + 5) * 4096);
      n2 = *(const float4*)(base + (size_t)(c + 6) * 4096);
      n3 = *(const float4*)(base + (size_t)(c + 7) * 4096);
    }
    *(float4*)(base + (size_t)(c + 0) * 4096) = S;
    S.x = fmaf(d64, S.x, u0.x); S.y = fmaf(d64, S.y, u0.y);
    S.z = fmaf(d64, S.z, u0.z); S.w = fmaf(d64, S.w, u0.w);
    *(float4*)(base + (size_t)(c + 1) * 4096) = S;
    S.x = fmaf(d64, S.x, u1.x); S.y = fmaf(d64, S.y, u1.y);
    S.z = fmaf(d64, S.z, u1.z); S.w = fmaf(d64, S.w, u1.w);
    *(float4*)(base + (size_t)(c + 2) * 4096) = S;
    S.x = fmaf(d64, S.x, u2.x); S.y = fmaf(d64, S.y, u2.y);
    S.z = fmaf(d64, S.z, u2.z); S.w = fmaf(d64, S.w, u2.w);
    *(float4*)(base + (size_t)(c + 3) * 4096) = S;
    S.x = fmaf(d64, S.x, u3.x); S.y = fmaf(d64, S.y, u3.y);
    S.z = fmaf(d64, S.z, u3.z); S.w = fmaf(d64, S.w, u3.w);
    u0 = n0; u1 = n1; u2 = n2; u3 = n3;
  }
}

// ---------------------------------------------------------------------------
// Phase C: o[u,i] = d_i^{u+1} * sum_j S_start[i][j] q_u[j]  + so[u,i]
// Writes FINAL scan output as bf16 (sob) for the MFMA out-projection.
// ---------------------------------------------------------------------------
__global__ __launch_bounds__(256) void scan_chunk_c(
    const float* __restrict__ qkv, const float* __restrict__ decay,
    const float* __restrict__ Sbuf, const float* __restrict__ so,
    __bf16* __restrict__ sob)
{
  __shared__ float Ss[64 * PAD];
  __shared__ float Qs[64 * PAD];
  __shared__ float l2d[64];

  const int tid = threadIdx.x;
  const int bc  = blockIdx.x;
  const int b   = bc >> 6;
  const int ch  = bc & 63;
  const int ti  = tid >> 4;
  const int tj  = tid & 15;

  #pragma unroll
  for (int it = 0; it < 4; ++it) {
    int idx = tid + it * 256;
    int row = idx >> 4, col4 = idx & 15;
    float4 s4 = *(const float4*)(Sbuf + (size_t)bc * 4096 + (size_t)row * 64 + col4 * 4);
    *ldsP(Ss, row, col4) = s4;
    float4 q4 = *(const float4*)(qkv + ((size_t)(b * Tt + ch * 64 + row)) * 192 + col4 * 4);
    *ldsP(Qs, row, col4) = q4;
  }
  if (tid < 64) {
    float d = 1.0f / (1.0f + expf(-decay[tid]));
    l2d[tid] = log2f(d);
  }
  __syncthreads();

  float acc[4][4] = {};
  #pragma unroll
  for (int j4 = 0; j4 < 16; ++j4) {
    float4 Q4[4], S4[4];
    #pragma unroll
    for (int r = 0; r < 4; ++r) Q4[r] = *ldsP(Qs, ti * 4 + r, j4);
    #pragma unroll
    for (int c = 0; c < 4; ++c) S4[c] = *ldsP(Ss, tj * 4 + c, j4);
    #pragma unroll
    for (int r = 0; r < 4; ++r)
      #pragma unroll
      for (int c = 0; c < 4; ++c) {
        acc[r][c] = fmaf(Q4[r].x, S4[c].x, acc[r][c]);
        acc[r][c] = fmaf(Q4[r].y, S4[c].y, acc[r][c]);
        acc[r][c] = fmaf(Q4[r].z, S4[c].z, acc[r][c]);
        acc[r][c] = fmaf(Q4[r].w, S4[c].w, acc[r][c]);
      }
  }

  #pragma unroll
  for (int r = 0; r < 4; ++r) {
    int u = ti * 4 + r;
    size_t row = (size_t)(b * Tt + ch * 64 + u);
    float4 prev = *(const float4*)(so + row * 64 + tj * 4);
    float e0 = exp2f((float)(u + 1) * l2d[tj * 4 + 0]);
    float e1 = exp2f((float)(u + 1) * l2d[tj * 4 + 1]);
    float e2 = exp2f((float)(u + 1) * l2d[tj * 4 + 2]);
    float e3 = exp2f((float)(u + 1) * l2d[tj * 4 + 3]);
    bf16x4v ov;
    ov[0] = (__bf16)fmaf(acc[r][0], e0, prev.x);
    ov[1] = (__bf16)fmaf(acc[r][1], e1, prev.y);
    ov[2] = (__bf16)fmaf(acc[r][2], e2, prev.z);
    ov[3] = (__bf16)fmaf(acc[r][3], e3, prev.w);
    *(bf16x4v*)(sob + row * 64 + tj * 4) = ov;
  }
}

// ---------------------------------------------------------------------------
// Kernel 3: out[M][1024] = x + sob[M][64] @ Wo^T + bo via MFMA, no LDS.
// Operand-swapped (A=Wo rows j, B=sob rows m) -> lane stores float4 along j.
// Block 256 thr = 4 waves (2 m x 2 j); block tile 128x128; wave tile 64x64.
// ---------------------------------------------------------------------------
__global__ __launch_bounds__(256) void out_mfma(
    const float* __restrict__ x, const __bf16* __restrict__ sob,
    const __bf16* __restrict__ Wob, const float* __restrict__ bo,
    float* __restrict__ out)
{
  const int bid = blockIdx.x;
  const int rb  = bid >> 3;
  const int cb  = bid & 7;
  const int w   = threadIdx.x >> 6;
  const int l   = threadIdx.x & 63;
  const int wr  = w >> 1;
  const int wc  = w & 1;
  const int m0  = rb * 128 + wr * 64;
  const int c0  = cb * 128 + wc * 64;
  const int lr  = l & 15;
  const int lk  = l >> 4;

  f32x4 acc[4][4] = {};   // [jf][mf]

  const __bf16* ap = Wob + (size_t)(c0 + lr) * 64 + lk * 8;   // A: Wo rows j
  const __bf16* bp = sob + (size_t)(m0 + lr) * 64 + lk * 8;   // B: sob rows m

  #pragma unroll
  for (int ks = 0; ks < 2; ++ks) {
    bf16x8 a[4], b[4];
    #pragma unroll
    for (int jf = 0; jf < 4; ++jf)
      a[jf] = *(const bf16x8*)(ap + (size_t)jf * 16 * 64 + ks * 32);
    #pragma unroll
    for (int mf = 0; mf < 4; ++mf)
      b[mf] = *(const bf16x8*)(bp + (size_t)mf * 16 * 64 + ks * 32);
    #pragma unroll
    for (int jf = 0; jf < 4; ++jf)
      #pragma unroll
      for (int mf = 0; mf < 4; ++mf)
        acc[jf][mf] = __builtin_amdgcn_mfma_f32_16x16x32_bf16(
            a[jf], b[mf], acc[jf][mf], 0, 0, 0);
  }

  // epilogue: j = c0 + jf*16 + lk*4 + r (contig), m = m0 + mf*16 + lr
  #pragma unroll
  for (int jf = 0; jf < 4; ++jf) {
    int j0 = c0 + jf * 16 + lk * 4;
    float4 b4 = *(const float4*)(bo + j0);
    #pragma unroll
    for (int mf = 0; mf < 4; ++mf) {
      size_t m = (size_t)m0 + mf * 16 + lr;
      float4 xv = *(const float4*)(x + m * 1024 + j0);
      float4 o;
      o.x = xv.x + acc[jf][mf][0] + b4.x;
      o.y = xv.y + acc[jf][mf][1] + b4.y;
      o.z = xv.z + acc[jf][mf][2] + b4.z;
      o.w = xv.w + acc[jf][mf][3] + b4.w;
      *(float4*)(out + m * 1024 + j0) = o;
    }
  }
}

// ---------------------------------------------------------------------------
extern "C" void kernel_launch(void* const* d_in, const int* in_sizes, int n_in,
                              void* d_out, int out_size, void* d_ws, size_t ws_size,
                              hipStream_t stream)
{
  const float* x   = (const float*)d_in[0];
  const float* Wq  = (const float*)d_in[1];
  const float* bq  = (const float*)d_in[2];
  const float* Wk  = (const float*)d_in[3];
  const float* bk  = (const float*)d_in[4];
  const float* Wv  = (const float*)d_in[5];
  const float* bv  = (const float*)d_in[6];
  const float* dec = (const float*)d_in[7];
  const float* Wo  = (const float*)d_in[8];
  const float* bo  = (const float*)d_in[9];
  float* out = (float*)d_out;

  float*  qkv   = (float*)d_ws;                    // [M][192] fp32 = 25.2 MB
  float*  so    = qkv + (size_t)Mm * 192;          // [M][64]  fp32 =  8.4 MB
  float*  Ubuf  = so + (size_t)Mm * 64;            // [512][64][64] =  8.4 MB
  __bf16* sob   = (__bf16*)(Ubuf + (size_t)512 * 4096);  // [M][64] bf16 = 4.2 MB
  __bf16* Wqkvb = sob + (size_t)Mm * 64;           // [192][1024]
  __bf16* Wob   = Wqkvb + (size_t)192 * 1024;      // [1024][64]

  convert_w<<<768, 256, 0, stream>>>(Wq, Wk, Wv, Wo, Wqkvb, Wob);
  qkv_mfma<<<Mm / 64, 256, 0, stream>>>(x, Wqkvb, bq, bk, bv, qkv);
  scan_chunk_a<<<512, 256, 0, stream>>>(qkv, dec, Ubuf, so);
  scan_state<<<32, 256, 0, stream>>>(dec, Ubuf);
  scan_chunk_c<<<512, 256, 0, stream>>>(qkv, dec, Ubuf, so, sob);
  out_mfma<<<2048, 256, 0, stream>>>(x, sob, Wob, bo, out);
}

// Round 8
// 368.710 us; speedup vs baseline: 3.5922x; 1.0543x over previous
//
#include <hip/hip_runtime.h>
#include <cstdint>
#include <cstddef>
#include <cmath>

#define Bb 8
#define Tt 4096
#define Dd 1024
#define DS 64
#define Mm (Bb*Tt)   // 32768
#define PAD 68       // floats per LDS row (fp32 scan tiles)

typedef __bf16 bf16x8 __attribute__((ext_vector_type(8)));
typedef __bf16 bf16x4v __attribute__((ext_vector_type(4)));
typedef float f32x4 __attribute__((ext_vector_type(4)));

// float4 pointer into a [64][PAD] fp32 LDS tile, XOR-swizzled (scan kernels)
__device__ __forceinline__ float4* ldsP(float* buf, int row, int col4) {
  return (float4*)(buf + row * PAD + (((col4) ^ ((row >> 3) & 7)) << 2));
}

// ---------------------------------------------------------------------------
// convert_w: Wq|Wk|Wv (stacked [192][1024]) and Wo ([1024][64]) -> bf16
// ---------------------------------------------------------------------------
__global__ __launch_bounds__(256) void convert_w(
    const float* __restrict__ Wq, const float* __restrict__ Wk,
    const float* __restrict__ Wv, const float* __restrict__ Wo,
    __bf16* __restrict__ Wqkvb, __bf16* __restrict__ Wob)
{
  int idx = blockIdx.x * 256 + threadIdx.x;
  if (idx < 196608) {
    float v = (idx < 65536) ? Wq[idx]
            : (idx < 131072) ? Wk[idx - 65536] : Wv[idx - 131072];
    Wqkvb[idx] = (__bf16)v;
  }
  if (idx < 65536) Wob[idx] = (__bf16)Wo[idx];
}

// ---------------------------------------------------------------------------
// Kernel 1: QKV projection via MFMA, operand-swapped (A=W rows j, B=x rows m).
// x tile staged fp32->bf16 in LDS once per block. Staging mapping gives
// 4 rows x 256B contiguous per load instruction (was 64 rows x 16B).
// Block 256 thr = 4 waves; wave w: cols c0=w*48 (3 j-frags), rows m0..m0+63.
// ---------------------------------------------------------------------------
__global__ __launch_bounds__(256) void qkv_mfma(
    const float* __restrict__ x, const __bf16* __restrict__ Wb,
    const float* __restrict__ bq, const float* __restrict__ bk,
    const float* __restrict__ bv, float* __restrict__ qkv)
{
  __shared__ __bf16 xs[64 * 64];   // [row m][k] bf16, 8KB, XOR-swizzled

  const int tid = threadIdx.x;
  const int w   = tid >> 6;
  const int l   = tid & 63;
  const int m0  = blockIdx.x * 64;
  const int c0  = w * 48;
  const int lr  = l & 15;
  const int lk  = l >> 4;

  // staging role: rows (tid>>4)+16g (g=0..3), k-col4 = tid&15
  const int sr0 = tid >> 4;          // 0..15
  const int sc4 = tid & 15;          // float4 index within 64-col k tile
  const float* xsrc = x + (size_t)(m0 + sr0) * 1024 + sc4 * 4;

  f32x4 acc[3][4] = {};   // [jf][mf]

  float4 f[4];
  #pragma unroll
  for (int g = 0; g < 4; ++g)
    f[g] = *(const float4*)(xsrc + (size_t)g * 16 * 1024);

  for (int k0 = 0; k0 < 1024; k0 += 64) {
    bf16x4v h[4];
    #pragma unroll
    for (int g = 0; g < 4; ++g) {
      h[g][0] = (__bf16)f[g].x; h[g][1] = (__bf16)f[g].y;
      h[g][2] = (__bf16)f[g].z; h[g][3] = (__bf16)f[g].w;
    }

    __syncthreads();   // previous iter's LDS reads complete
    #pragma unroll
    for (int g = 0; g < 4; ++g) {
      int row = sr0 + 16 * g;
      *(bf16x4v*)((char*)xs + row * 128 + ((sc4 * 8) ^ ((row & 7) << 4))) = h[g];
    }
    __syncthreads();   // writes visible

    if (k0 + 64 < 1024) {
      #pragma unroll
      for (int g = 0; g < 4; ++g)
        f[g] = *(const float4*)(xsrc + (size_t)g * 16 * 1024 + k0 + 64);
    }

    #pragma unroll
    for (int ks = 0; ks < 2; ++ks) {
      bf16x8 wf[3], xf[4];
      #pragma unroll
      for (int jf = 0; jf < 3; ++jf)
        wf[jf] = *(const bf16x8*)(Wb + (size_t)(c0 + jf * 16 + lr) * 1024
                                     + k0 + ks * 32 + lk * 8);
      #pragma unroll
      for (int mf = 0; mf < 4; ++mf) {
        int row = mf * 16 + lr;
        int boff = row * 128 + ((ks * 64 + lk * 16) ^ ((row & 7) << 4));
        xf[mf] = *(const bf16x8*)((const char*)xs + boff);
      }
      #pragma unroll
      for (int jf = 0; jf < 3; ++jf)
        #pragma unroll
        for (int mf = 0; mf < 4; ++mf)
          acc[jf][mf] = __builtin_amdgcn_mfma_f32_16x16x32_bf16(
              wf[jf], xf[mf], acc[jf][mf], 0, 0, 0);
    }
  }

  // epilogue: j = c0 + jf*16 + lk*4 + r (contiguous), m = m0 + mf*16 + lr
  #pragma unroll
  for (int jf = 0; jf < 3; ++jf) {
    int j0 = c0 + jf * 16 + lk * 4;
    const float* bsrc = (j0 < 64) ? (bq + j0)
                      : (j0 < 128) ? (bk + j0 - 64) : (bv + j0 - 128);
    float4 b4 = *(const float4*)bsrc;
    #pragma unroll
    for (int mf = 0; mf < 4; ++mf) {
      int m = m0 + mf * 16 + lr;
      float4 o;
      o.x = acc[jf][mf][0] + b4.x;
      o.y = acc[jf][mf][1] + b4.y;
      o.z = acc[jf][mf][2] + b4.z;
      o.w = acc[jf][mf][3] + b4.w;
      *(float4*)(qkv + (size_t)m * 192 + j0) = o;
    }
  }
}

// ---------------------------------------------------------------------------
// Phase A: per (b,chunk): G = causal(Q K^T) (stored transposed GT[s][u]),
//   Vt[s,i] = v_s[i] * d_i^{-s},
//   U[i,j]  = d_i^63 * sum_s Vt[s,i] K[s,j]      -> Ubuf
//   intra[u,i] = d_i^u * sum_s GT[s,u] Vt[s,i]   -> so (phase C adds to it)
// ---------------------------------------------------------------------------
__global__ __launch_bounds__(256) void scan_chunk_a(
    const float* __restrict__ qkv, const float* __restrict__ decay,
    float* __restrict__ Ubuf, float* __restrict__ so)
{
  __shared__ float Qs[64 * PAD];   // later overwritten with GT
  __shared__ float Ks[64 * PAD];
  __shared__ float Vs[64 * PAD];   // scaled to Vt in place
  __shared__ float l2d[64];

  const int tid = threadIdx.x;
  const int bc  = blockIdx.x;          // b*64 + ch
  const int b   = bc >> 6;
  const int ch  = bc & 63;
  const int ti  = tid >> 4;
  const int tj  = tid & 15;

  const float* base = qkv + ((size_t)(b * Tt + ch * 64)) * 192;

  #pragma unroll
  for (int it = 0; it < 12; ++it) {
    int idx = tid + it * 256;
    int row = idx / 48, f = idx % 48;
    float4 g = *(const float4*)(base + (size_t)row * 192 + f * 4);
    float4* dst;
    if (f < 16)      dst = ldsP(Qs, row, f);
    else if (f < 32) dst = ldsP(Ks, row, f - 16);
    else             dst = ldsP(Vs, row, f - 32);
    *dst = g;
  }
  if (tid < 64) {
    float d = 1.0f / (1.0f + expf(-decay[tid]));
    l2d[tid] = log2f(d);
  }
  __syncthreads();

  {
    int s = tid >> 2;
    #pragma unroll
    for (int g4 = 0; g4 < 4; ++g4) {
      int col4 = (tid & 3) * 4 + g4;
      float4* p = ldsP(Vs, s, col4);
      float4 v = *p;
      float e0 = exp2f(-(float)s * l2d[col4 * 4 + 0]);
      float e1 = exp2f(-(float)s * l2d[col4 * 4 + 1]);
      float e2 = exp2f(-(float)s * l2d[col4 * 4 + 2]);
      float e3 = exp2f(-(float)s * l2d[col4 * 4 + 3]);
      v.x *= e0; v.y *= e1; v.z *= e2; v.w *= e3;
      *p = v;
    }
  }

  float gval[4][4] = {};
  #pragma unroll
  for (int kk4 = 0; kk4 < 16; ++kk4) {
    float4 K4[4], Q4[4];
    #pragma unroll
    for (int r = 0; r < 4; ++r) K4[r] = *ldsP(Ks, ti * 4 + r, kk4);
    #pragma unroll
    for (int c = 0; c < 4; ++c) Q4[c] = *ldsP(Qs, tj * 4 + c, kk4);
    #pragma unroll
    for (int r = 0; r < 4; ++r)
      #pragma unroll
      for (int c = 0; c < 4; ++c) {
        gval[r][c] = fmaf(K4[r].x, Q4[c].x, gval[r][c]);
        gval[r][c] = fmaf(K4[r].y, Q4[c].y, gval[r][c]);
        gval[r][c] = fmaf(K4[r].z, Q4[c].z, gval[r][c]);
        gval[r][c] = fmaf(K4[r].w, Q4[c].w, gval[r][c]);
      }
  }
  #pragma unroll
  for (int r = 0; r < 4; ++r)
    #pragma unroll
    for (int c = 0; c < 4; ++c)
      if (ti * 4 + r > tj * 4 + c) gval[r][c] = 0.0f;

  __syncthreads();

  #pragma unroll
  for (int r = 0; r < 4; ++r) {
    float4 g4 = {gval[r][0], gval[r][1], gval[r][2], gval[r][3]};
    *ldsP(Qs, ti * 4 + r, tj) = g4;
  }
  __syncthreads();

  float uacc[4][4] = {};
  float oacc[4][4] = {};
  for (int s = 0; s < 64; ++s) {
    float4 Vti = *ldsP(Vs, s, ti);
    float4 Ktj = *ldsP(Ks, s, tj);
    float4 Gti = *ldsP(Qs, s, ti);
    float4 Vtj = *ldsP(Vs, s, tj);
    const float vi[4] = {Vti.x, Vti.y, Vti.z, Vti.w};
    const float kj[4] = {Ktj.x, Ktj.y, Ktj.z, Ktj.w};
    const float gu[4] = {Gti.x, Gti.y, Gti.z, Gti.w};
    const float vj[4] = {Vtj.x, Vtj.y, Vtj.z, Vtj.w};
    #pragma unroll
    for (int r = 0; r < 4; ++r)
      #pragma unroll
      for (int c = 0; c < 4; ++c) {
        uacc[r][c] = fmaf(vi[r], kj[c], uacc[r][c]);
        oacc[r][c] = fmaf(gu[r], vj[c], oacc[r][c]);
      }
  }

  #pragma unroll
  for (int r = 0; r < 4; ++r) {
    int i = ti * 4 + r;
    float d63 = exp2f(63.0f * l2d[i]);
    float4 o = {uacc[r][0] * d63, uacc[r][1] * d63,
                uacc[r][2] * d63, uacc[r][3] * d63};
    *(float4*)(Ubuf + ((size_t)bc * 64 + i) * 64 + tj * 4) = o;
  }
  #pragma unroll
  for (int r = 0; r < 4; ++r) {
    int u = ti * 4 + r;
    float e0 = exp2f((float)u * l2d[tj * 4 + 0]);
    float e1 = exp2f((float)u * l2d[tj * 4 + 1]);
    float e2 = exp2f((float)u * l2d[tj * 4 + 2]);
    float e3 = exp2f((float)u * l2d[tj * 4 + 3]);
    float4 o = {oacc[r][0] * e0, oacc[r][1] * e1,
                oacc[r][2] * e2, oacc[r][3] * e3};
    *(float4*)(so + ((size_t)(b * Tt + ch * 64 + u)) * 64 + tj * 4) = o;
  }
}

// ---------------------------------------------------------------------------
// Phase B: sequential over 64 chunks; in-place U -> S_start. 4-deep prefetch.
// 128 blocks x 64 thr (finer j split -> 4x parallelism vs round 6).
// ---------------------------------------------------------------------------
__global__ __launch_bounds__(64) void scan_state(
    const float* __restrict__ decay, float* __restrict__ Ubuf)
{
  const int b  = blockIdx.x >> 4;
  const int jq = blockIdx.x & 15;
  const int i  = threadIdx.x;

  float d = 1.0f / (1.0f + expf(-decay[i]));
  float d2 = d * d, d4 = d2 * d2, d8 = d4 * d4;
  float d16 = d8 * d8, d32 = d16 * d16, d64 = d32 * d32;

  float* base = Ubuf + ((size_t)b * 64) * 4096 + (size_t)i * 64 + jq * 4;

  float4 S = {0.f, 0.f, 0.f, 0.f};
  float4 u0 = *(const float4*)(base + 0 * 4096);
  float4 u1 = *(const float4*)(base + 1 * 4096);
  float4 u2 = *(const float4*)(base + 2 * 4096);
  float4 u3 = *(const float4*)(base + 3 * 4096);

  for (int c = 0; c < 64; c += 4) {
    float4 n0 = u0, n1 = u1, n2 = u2, n3 = u3;
    if (c + 4 < 64) {
      n0 = *(const float4*)(base + (size_t)(c + 4) * 4096);
      n1 = *(const float4*)(base + (size_t)(c + 5) * 4096);
      n2 = *(const float4*)(base + (size_t)(c + 6) * 4096);
      n3 = *(const float4*)(base + (size_t)(c + 7) * 4096);
    }
    *(float4*)(base + (size_t)(c + 0) * 4096) = S;
    S.x = fmaf(d64, S.x, u0.x); S.y = fmaf(d64, S.y, u0.y);
    S.z = fmaf(d64, S.z, u0.z); S.w = fmaf(d64, S.w, u0.w);
    *(float4*)(base + (size_t)(c + 1) * 4096) = S;
    S.x = fmaf(d64, S.x, u1.x); S.y = fmaf(d64, S.y, u1.y);
    S.z = fmaf(d64, S.z, u1.z); S.w = fmaf(d64, S.w, u1.w);
    *(float4*)(base + (size_t)(c + 2) * 4096) = S;
    S.x = fmaf(d64, S.x, u2.x); S.y = fmaf(d64, S.y, u2.y);
    S.z = fmaf(d64, S.z, u2.z); S.w = fmaf(d64, S.w, u2.w);
    *(float4*)(base + (size_t)(c + 3) * 4096) = S;
    S.x = fmaf(d64, S.x, u3.x); S.y = fmaf(d64, S.y, u3.y);
    S.z = fmaf(d64, S.z, u3.z); S.w = fmaf(d64, S.w, u3.w);
    u0 = n0; u1 = n1; u2 = n2; u3 = n3;
  }
}

// ---------------------------------------------------------------------------
// Phase C: o[u,i] = d_i^{u+1} * sum_j S_start[i][j] q_u[j]  + so[u,i]
// Writes FINAL scan output as bf16 (sob) for the MFMA out-projection.
// ---------------------------------------------------------------------------
__global__ __launch_bounds__(256) void scan_chunk_c(
    const float* __restrict__ qkv, const float* __restrict__ decay,
    const float* __restrict__ Sbuf, const float* __restrict__ so,
    __bf16* __restrict__ sob)
{
  __shared__ float Ss[64 * PAD];
  __shared__ float Qs[64 * PAD];
  __shared__ float l2d[64];

  const int tid = threadIdx.x;
  const int bc  = blockIdx.x;
  const int b   = bc >> 6;
  const int ch  = bc & 63;
  const int ti  = tid >> 4;
  const int tj  = tid & 15;

  #pragma unroll
  for (int it = 0; it < 4; ++it) {
    int idx = tid + it * 256;
    int row = idx >> 4, col4 = idx & 15;
    float4 s4 = *(const float4*)(Sbuf + (size_t)bc * 4096 + (size_t)row * 64 + col4 * 4);
    *ldsP(Ss, row, col4) = s4;
    float4 q4 = *(const float4*)(qkv + ((size_t)(b * Tt + ch * 64 + row)) * 192 + col4 * 4);
    *ldsP(Qs, row, col4) = q4;
  }
  if (tid < 64) {
    float d = 1.0f / (1.0f + expf(-decay[tid]));
    l2d[tid] = log2f(d);
  }
  __syncthreads();

  float acc[4][4] = {};
  #pragma unroll
  for (int j4 = 0; j4 < 16; ++j4) {
    float4 Q4[4], S4[4];
    #pragma unroll
    for (int r = 0; r < 4; ++r) Q4[r] = *ldsP(Qs, ti * 4 + r, j4);
    #pragma unroll
    for (int c = 0; c < 4; ++c) S4[c] = *ldsP(Ss, tj * 4 + c, j4);
    #pragma unroll
    for (int r = 0; r < 4; ++r)
      #pragma unroll
      for (int c = 0; c < 4; ++c) {
        acc[r][c] = fmaf(Q4[r].x, S4[c].x, acc[r][c]);
        acc[r][c] = fmaf(Q4[r].y, S4[c].y, acc[r][c]);
        acc[r][c] = fmaf(Q4[r].z, S4[c].z, acc[r][c]);
        acc[r][c] = fmaf(Q4[r].w, S4[c].w, acc[r][c]);
      }
  }

  #pragma unroll
  for (int r = 0; r < 4; ++r) {
    int u = ti * 4 + r;
    size_t row = (size_t)(b * Tt + ch * 64 + u);
    float4 prev = *(const float4*)(so + row * 64 + tj * 4);
    float e0 = exp2f((float)(u + 1) * l2d[tj * 4 + 0]);
    float e1 = exp2f((float)(u + 1) * l2d[tj * 4 + 1]);
    float e2 = exp2f((float)(u + 1) * l2d[tj * 4 + 2]);
    float e3 = exp2f((float)(u + 1) * l2d[tj * 4 + 3]);
    bf16x4v ov;
    ov[0] = (__bf16)fmaf(acc[r][0], e0, prev.x);
    ov[1] = (__bf16)fmaf(acc[r][1], e1, prev.y);
    ov[2] = (__bf16)fmaf(acc[r][2], e2, prev.z);
    ov[3] = (__bf16)fmaf(acc[r][3], e3, prev.w);
    *(bf16x4v*)(sob + row * 64 + tj * 4) = ov;
  }
}

// ---------------------------------------------------------------------------
// Kernel 3: out[M][1024] = x + sob[M][64] @ Wo^T + bo via MFMA.
// v3: wave owns 16 rows x all 1024 cols; loops 16 j-blocks of 64.
// D-frags staged through per-wave 4KB XOR-swizzled LDS (wave-synchronous,
// no barriers) so x-load / out-store instructions cover 4 rows x 256B.
// Block 256 thr = 4 waves = 64 rows; grid 512.
// ---------------------------------------------------------------------------
__global__ __launch_bounds__(256) void out_mfma(
    const float* __restrict__ x, const __bf16* __restrict__ sob,
    const __bf16* __restrict__ Wob, const float* __restrict__ bo,
    float* __restrict__ out)
{
  __shared__ float ps[4][16 * 64];   // per-wave staging, 4KB each

  const int w  = threadIdx.x >> 6;
  const int l  = threadIdx.x & 63;
  const int lr = l & 15;
  const int lk = l >> 4;
  const int m0 = blockIdx.x * 64 + w * 16;   // wave's 16 rows
  const int er = l >> 4;                     // epilogue row group 0..3
  const int ec = l & 15;                     // epilogue col4

  // B operand: sob rows m0+lr (reused across all j-blocks)
  const __bf16* bp = sob + (size_t)(m0 + lr) * 64 + lk * 8;
  bf16x8 bf0 = *(const bf16x8*)(bp);
  bf16x8 bf1 = *(const bf16x8*)(bp + 32);

  float* myps = ps[w];

  for (int jblk = 0; jblk < 16; ++jblk) {
    const int j0 = jblk * 64;

    // issue x loads early (hide HBM latency under MFMA+LDS)
    float4 xv[4];
    #pragma unroll
    for (int k = 0; k < 4; ++k)
      xv[k] = *(const float4*)(x + (size_t)(m0 + er + 4 * k) * 1024 + j0 + ec * 4);
    float4 b4 = *(const float4*)(bo + j0 + ec * 4);

    // A operands: Wob rows j (L2-resident), 4 j-frags x K=64
    const __bf16* ap = Wob + (size_t)(j0 + lr) * 64 + lk * 8;
    f32x4 acc[4];
    #pragma unroll
    for (int jf = 0; jf < 4; ++jf) {
      bf16x8 a0 = *(const bf16x8*)(ap + (size_t)jf * 16 * 64);
      bf16x8 a1 = *(const bf16x8*)(ap + (size_t)jf * 16 * 64 + 32);
      f32x4 t = {0.f, 0.f, 0.f, 0.f};
      t = __builtin_amdgcn_mfma_f32_16x16x32_bf16(a0, bf0, t, 0, 0, 0);
      t = __builtin_amdgcn_mfma_f32_16x16x32_bf16(a1, bf1, t, 0, 0, 0);
      acc[jf] = t;
    }

    // stage D-frags to LDS: thread at (row lr, col4 jf*4+lk), XOR-swizzled
    #pragma unroll
    for (int jf = 0; jf < 4; ++jf) {
      int c4 = jf * 4 + lk;
      float4 v = {acc[jf][0], acc[jf][1], acc[jf][2], acc[jf][3]};
      *(float4*)((char*)myps + lr * 256 + ((c4 * 16) ^ ((lr & 7) << 4))) = v;
    }

    // wave-synchronous readback (DS ops in-order within a wave), add, store
    #pragma unroll
    for (int k = 0; k < 4; ++k) {
      int r = er + 4 * k;
      float4 pv = *(const float4*)((char*)myps + r * 256 + ((ec * 16) ^ ((r & 7) << 4)));
      size_t m = (size_t)(m0 + r);
      float4 o;
      o.x = xv[k].x + pv.x + b4.x;
      o.y = xv[k].y + pv.y + b4.y;
      o.z = xv[k].z + pv.z + b4.z;
      o.w = xv[k].w + pv.w + b4.w;
      *(float4*)(out + m * 1024 + j0 + ec * 4) = o;
    }
  }
}

// ---------------------------------------------------------------------------
extern "C" void kernel_launch(void* const* d_in, const int* in_sizes, int n_in,
                              void* d_out, int out_size, void* d_ws, size_t ws_size,
                              hipStream_t stream)
{
  const float* x   = (const float*)d_in[0];
  const float* Wq  = (const float*)d_in[1];
  const float* bq  = (const float*)d_in[2];
  const float* Wk  = (const float*)d_in[3];
  const float* bk  = (const float*)d_in[4];
  const float* Wv  = (const float*)d_in[5];
  const float* bv  = (const float*)d_in[6];
  const float* dec = (const float*)d_in[7];
  const float* Wo  = (const float*)d_in[8];
  const float* bo  = (const float*)d_in[9];
  float* out = (float*)d_out;

  float*  qkv   = (float*)d_ws;                    // [M][192] fp32 = 25.2 MB
  float*  so    = qkv + (size_t)Mm * 192;          // [M][64]  fp32 =  8.4 MB
  float*  Ubuf  = so + (size_t)Mm * 64;            // [512][64][64] =  8.4 MB
  __bf16* sob   = (__bf16*)(Ubuf + (size_t)512 * 4096);  // [M][64] bf16 = 4.2 MB
  __bf16* Wqkvb = sob + (size_t)Mm * 64;           // [192][1024]
  __bf16* Wob   = Wqkvb + (size_t)192 * 1024;      // [1024][64]

  convert_w<<<768, 256, 0, stream>>>(Wq, Wk, Wv, Wo, Wqkvb, Wob);
  qkv_mfma<<<Mm / 64, 256, 0, stream>>>(x, Wqkvb, bq, bk, bv, qkv);
  scan_chunk_a<<<512, 256, 0, stream>>>(qkv, dec, Ubuf, so);
  scan_state<<<128, 64, 0, stream>>>(dec, Ubuf);
  scan_chunk_c<<<512, 256, 0, stream>>>(qkv, dec, Ubuf, so, sob);
  out_mfma<<<512, 256, 0, stream>>>(x, sob, Wob, bo, out);
}

// Round 9
// 360.113 us; speedup vs baseline: 3.6779x; 1.0239x over previous
//
#include <hip/hip_runtime.h>
#include <cstdint>
#include <cstddef>
#include <cmath>

#define Bb 8
#define Tt 4096
#define Dd 1024
#define DS 64
#define Mm (Bb*Tt)   // 32768
#define PAD 68       // floats per LDS row (fp32 scan tiles)

typedef __bf16 bf16x8 __attribute__((ext_vector_type(8)));
typedef __bf16 bf16x4v __attribute__((ext_vector_type(4)));
typedef float f32x4 __attribute__((ext_vector_type(4)));

// float4 pointer into a [64][PAD] fp32 LDS tile, XOR-swizzled (scan kernels)
__device__ __forceinline__ float4* ldsP(float* buf, int row, int col4) {
  return (float4*)(buf + row * PAD + (((col4) ^ ((row >> 3) & 7)) << 2));
}

// ---------------------------------------------------------------------------
// convert_w: Wq|Wk|Wv (stacked [192][1024]) and Wo ([1024][64]) -> bf16
// ---------------------------------------------------------------------------
__global__ __launch_bounds__(256) void convert_w(
    const float* __restrict__ Wq, const float* __restrict__ Wk,
    const float* __restrict__ Wv, const float* __restrict__ Wo,
    __bf16* __restrict__ Wqkvb, __bf16* __restrict__ Wob)
{
  int idx = blockIdx.x * 256 + threadIdx.x;
  if (idx < 196608) {
    float v = (idx < 65536) ? Wq[idx]
            : (idx < 131072) ? Wk[idx - 65536] : Wv[idx - 131072];
    Wqkvb[idx] = (__bf16)v;
  }
  if (idx < 65536) Wob[idx] = (__bf16)Wo[idx];
}

// ---------------------------------------------------------------------------
// Kernel 1: QKV projection via MFMA, operand-swapped (A=W rows j, B=x rows m).
// Double-buffered LDS staging: ONE barrier per 64-K step (was two).
// Block 256 thr = 4 waves; wave w: cols c0=w*48 (3 j-frags), rows m0..m0+63.
// ---------------------------------------------------------------------------
__global__ __launch_bounds__(256) void qkv_mfma(
    const float* __restrict__ x, const __bf16* __restrict__ Wb,
    const float* __restrict__ bq, const float* __restrict__ bk,
    const float* __restrict__ bv, float* __restrict__ qkv)
{
  __shared__ __bf16 xs[2][64 * 64];   // 2 x 8KB, XOR-swizzled

  const int tid = threadIdx.x;
  const int w   = tid >> 6;
  const int l   = tid & 63;
  const int m0  = blockIdx.x * 64;
  const int c0  = w * 48;
  const int lr  = l & 15;
  const int lk  = l >> 4;

  // staging role: rows (tid>>4)+16g (g=0..3), k-col4 = tid&15
  const int sr0 = tid >> 4;
  const int sc4 = tid & 15;
  const float* xsrc = x + (size_t)(m0 + sr0) * 1024 + sc4 * 4;

  f32x4 acc[3][4] = {};   // [jf][mf]

  // prologue: tile 0 -> regs -> xs[0]
  float4 f[4];
  #pragma unroll
  for (int g = 0; g < 4; ++g)
    f[g] = *(const float4*)(xsrc + (size_t)g * 16 * 1024);
  #pragma unroll
  for (int g = 0; g < 4; ++g) {
    bf16x4v h;
    h[0] = (__bf16)f[g].x; h[1] = (__bf16)f[g].y;
    h[2] = (__bf16)f[g].z; h[3] = (__bf16)f[g].w;
    int row = sr0 + 16 * g;
    *(bf16x4v*)((char*)xs[0] + row * 128 + ((sc4 * 8) ^ ((row & 7) << 4))) = h;
  }

  int cur = 0;
  for (int k0 = 0; k0 < 1024; k0 += 64) {
    const bool hasNext = (k0 + 64 < 1024);
    if (hasNext) {
      #pragma unroll
      for (int g = 0; g < 4; ++g)
        f[g] = *(const float4*)(xsrc + (size_t)g * 16 * 1024 + k0 + 64);
    }

    __syncthreads();   // xs[cur] writes visible; prior reads of xs[cur^1] done

    if (hasNext) {
      #pragma unroll
      for (int g = 0; g < 4; ++g) {
        bf16x4v h;
        h[0] = (__bf16)f[g].x; h[1] = (__bf16)f[g].y;
        h[2] = (__bf16)f[g].z; h[3] = (__bf16)f[g].w;
        int row = sr0 + 16 * g;
        *(bf16x4v*)((char*)xs[cur ^ 1] + row * 128 + ((sc4 * 8) ^ ((row & 7) << 4))) = h;
      }
    }

    #pragma unroll
    for (int ks = 0; ks < 2; ++ks) {
      bf16x8 wf[3], xf[4];
      #pragma unroll
      for (int jf = 0; jf < 3; ++jf)
        wf[jf] = *(const bf16x8*)(Wb + (size_t)(c0 + jf * 16 + lr) * 1024
                                     + k0 + ks * 32 + lk * 8);
      #pragma unroll
      for (int mf = 0; mf < 4; ++mf) {
        int row = mf * 16 + lr;
        int boff = row * 128 + ((ks * 64 + lk * 16) ^ ((row & 7) << 4));
        xf[mf] = *(const bf16x8*)((const char*)xs[cur] + boff);
      }
      #pragma unroll
      for (int jf = 0; jf < 3; ++jf)
        #pragma unroll
        for (int mf = 0; mf < 4; ++mf)
          acc[jf][mf] = __builtin_amdgcn_mfma_f32_16x16x32_bf16(
              wf[jf], xf[mf], acc[jf][mf], 0, 0, 0);
    }
    cur ^= 1;
  }

  // epilogue: j = c0 + jf*16 + lk*4 + r (contiguous), m = m0 + mf*16 + lr
  #pragma unroll
  for (int jf = 0; jf < 3; ++jf) {
    int j0 = c0 + jf * 16 + lk * 4;
    const float* bsrc = (j0 < 64) ? (bq + j0)
                      : (j0 < 128) ? (bk + j0 - 64) : (bv + j0 - 128);
    float4 b4 = *(const float4*)bsrc;
    #pragma unroll
    for (int mf = 0; mf < 4; ++mf) {
      int m = m0 + mf * 16 + lr;
      float4 o;
      o.x = acc[jf][mf][0] + b4.x;
      o.y = acc[jf][mf][1] + b4.y;
      o.z = acc[jf][mf][2] + b4.z;
      o.w = acc[jf][mf][3] + b4.w;
      *(float4*)(qkv + (size_t)m * 192 + j0) = o;
    }
  }
}

// ---------------------------------------------------------------------------
// Phase A: per (b,chunk): G = causal(Q K^T) (stored transposed GT[s][u]),
//   Vt[s,i] = v_s[i] * d_i^{-s},
//   U[i,j]  = d_i^63 * sum_s Vt[s,i] K[s,j]      -> Ubuf
//   intra[u,i] = d_i^u * sum_s GT[s,u] Vt[s,i]   -> so (phase C adds to it)
// ---------------------------------------------------------------------------
__global__ __launch_bounds__(256) void scan_chunk_a(
    const float* __restrict__ qkv, const float* __restrict__ decay,
    float* __restrict__ Ubuf, float* __restrict__ so)
{
  __shared__ float Qs[64 * PAD];   // later overwritten with GT
  __shared__ float Ks[64 * PAD];
  __shared__ float Vs[64 * PAD];   // scaled to Vt in place
  __shared__ float l2d[64];

  const int tid = threadIdx.x;
  const int bc  = blockIdx.x;          // b*64 + ch
  const int b   = bc >> 6;
  const int ch  = bc & 63;
  const int ti  = tid >> 4;
  const int tj  = tid & 15;

  const float* base = qkv + ((size_t)(b * Tt + ch * 64)) * 192;

  #pragma unroll
  for (int it = 0; it < 12; ++it) {
    int idx = tid + it * 256;
    int row = idx / 48, f = idx % 48;
    float4 g = *(const float4*)(base + (size_t)row * 192 + f * 4);
    float4* dst;
    if (f < 16)      dst = ldsP(Qs, row, f);
    else if (f < 32) dst = ldsP(Ks, row, f - 16);
    else             dst = ldsP(Vs, row, f - 32);
    *dst = g;
  }
  if (tid < 64) {
    float d = 1.0f / (1.0f + expf(-decay[tid]));
    l2d[tid] = log2f(d);
  }
  __syncthreads();

  {
    int s = tid >> 2;
    #pragma unroll
    for (int g4 = 0; g4 < 4; ++g4) {
      int col4 = (tid & 3) * 4 + g4;
      float4* p = ldsP(Vs, s, col4);
      float4 v = *p;
      float e0 = exp2f(-(float)s * l2d[col4 * 4 + 0]);
      float e1 = exp2f(-(float)s * l2d[col4 * 4 + 1]);
      float e2 = exp2f(-(float)s * l2d[col4 * 4 + 2]);
      float e3 = exp2f(-(float)s * l2d[col4 * 4 + 3]);
      v.x *= e0; v.y *= e1; v.z *= e2; v.w *= e3;
      *p = v;
    }
  }

  float gval[4][4] = {};
  #pragma unroll
  for (int kk4 = 0; kk4 < 16; ++kk4) {
    float4 K4[4], Q4[4];
    #pragma unroll
    for (int r = 0; r < 4; ++r) K4[r] = *ldsP(Ks, ti * 4 + r, kk4);
    #pragma unroll
    for (int c = 0; c < 4; ++c) Q4[c] = *ldsP(Qs, tj * 4 + c, kk4);
    #pragma unroll
    for (int r = 0; r < 4; ++r)
      #pragma unroll
      for (int c = 0; c < 4; ++c) {
        gval[r][c] = fmaf(K4[r].x, Q4[c].x, gval[r][c]);
        gval[r][c] = fmaf(K4[r].y, Q4[c].y, gval[r][c]);
        gval[r][c] = fmaf(K4[r].z, Q4[c].z, gval[r][c]);
        gval[r][c] = fmaf(K4[r].w, Q4[c].w, gval[r][c]);
      }
  }
  #pragma unroll
  for (int r = 0; r < 4; ++r)
    #pragma unroll
    for (int c = 0; c < 4; ++c)
      if (ti * 4 + r > tj * 4 + c) gval[r][c] = 0.0f;

  __syncthreads();

  #pragma unroll
  for (int r = 0; r < 4; ++r) {
    float4 g4 = {gval[r][0], gval[r][1], gval[r][2], gval[r][3]};
    *ldsP(Qs, ti * 4 + r, tj) = g4;
  }
  __syncthreads();

  float uacc[4][4] = {};
  float oacc[4][4] = {};
  for (int s = 0; s < 64; ++s) {
    float4 Vti = *ldsP(Vs, s, ti);
    float4 Ktj = *ldsP(Ks, s, tj);
    float4 Gti = *ldsP(Qs, s, ti);
    float4 Vtj = *ldsP(Vs, s, tj);
    const float vi[4] = {Vti.x, Vti.y, Vti.z, Vti.w};
    const float kj[4] = {Ktj.x, Ktj.y, Ktj.z, Ktj.w};
    const float gu[4] = {Gti.x, Gti.y, Gti.z, Gti.w};
    const float vj[4] = {Vtj.x, Vtj.y, Vtj.z, Vtj.w};
    #pragma unroll
    for (int r = 0; r < 4; ++r)
      #pragma unroll
      for (int c = 0; c < 4; ++c) {
        uacc[r][c] = fmaf(vi[r], kj[c], uacc[r][c]);
        oacc[r][c] = fmaf(gu[r], vj[c], oacc[r][c]);
      }
  }

  #pragma unroll
  for (int r = 0; r < 4; ++r) {
    int i = ti * 4 + r;
    float d63 = exp2f(63.0f * l2d[i]);
    float4 o = {uacc[r][0] * d63, uacc[r][1] * d63,
                uacc[r][2] * d63, uacc[r][3] * d63};
    *(float4*)(Ubuf + ((size_t)bc * 64 + i) * 64 + tj * 4) = o;
  }
  #pragma unroll
  for (int r = 0; r < 4; ++r) {
    int u = ti * 4 + r;
    float e0 = exp2f((float)u * l2d[tj * 4 + 0]);
    float e1 = exp2f((float)u * l2d[tj * 4 + 1]);
    float e2 = exp2f((float)u * l2d[tj * 4 + 2]);
    float e3 = exp2f((float)u * l2d[tj * 4 + 3]);
    float4 o = {oacc[r][0] * e0, oacc[r][1] * e1,
                oacc[r][2] * e2, oacc[r][3] * e3};
    *(float4*)(so + ((size_t)(b * Tt + ch * 64 + u)) * 64 + tj * 4) = o;
  }
}

// ---------------------------------------------------------------------------
// Phase B: sequential over 64 chunks; in-place U -> S_start. 4-deep prefetch.
// ---------------------------------------------------------------------------
__global__ __launch_bounds__(64) void scan_state(
    const float* __restrict__ decay, float* __restrict__ Ubuf)
{
  const int b  = blockIdx.x >> 4;
  const int jq = blockIdx.x & 15;
  const int i  = threadIdx.x;

  float d = 1.0f / (1.0f + expf(-decay[i]));
  float d2 = d * d, d4 = d2 * d2, d8 = d4 * d4;
  float d16 = d8 * d8, d32 = d16 * d16, d64 = d32 * d32;

  float* base = Ubuf + ((size_t)b * 64) * 4096 + (size_t)i * 64 + jq * 4;

  float4 S = {0.f, 0.f, 0.f, 0.f};
  float4 u0 = *(const float4*)(base + 0 * 4096);
  float4 u1 = *(const float4*)(base + 1 * 4096);
  float4 u2 = *(const float4*)(base + 2 * 4096);
  float4 u3 = *(const float4*)(base + 3 * 4096);

  for (int c = 0; c < 64; c += 4) {
    float4 n0 = u0, n1 = u1, n2 = u2, n3 = u3;
    if (c + 4 < 64) {
      n0 = *(const float4*)(base + (size_t)(c + 4) * 4096);
      n1 = *(const float4*)(base + (size_t)(c + 5) * 4096);
      n2 = *(const float4*)(base + (size_t)(c + 6) * 4096);
      n3 = *(const float4*)(base + (size_t)(c + 7) * 4096);
    }
    *(float4*)(base + (size_t)(c + 0) * 4096) = S;
    S.x = fmaf(d64, S.x, u0.x); S.y = fmaf(d64, S.y, u0.y);
    S.z = fmaf(d64, S.z, u0.z); S.w = fmaf(d64, S.w, u0.w);
    *(float4*)(base + (size_t)(c + 1) * 4096) = S;
    S.x = fmaf(d64, S.x, u1.x); S.y = fmaf(d64, S.y, u1.y);
    S.z = fmaf(d64, S.z, u1.z); S.w = fmaf(d64, S.w, u1.w);
    *(float4*)(base + (size_t)(c + 2) * 4096) = S;
    S.x = fmaf(d64, S.x, u2.x); S.y = fmaf(d64, S.y, u2.y);
    S.z = fmaf(d64, S.z, u2.z); S.w = fmaf(d64, S.w, u2.w);
    *(float4*)(base + (size_t)(c + 3) * 4096) = S;
    S.x = fmaf(d64, S.x, u3.x); S.y = fmaf(d64, S.y, u3.y);
    S.z = fmaf(d64, S.z, u3.z); S.w = fmaf(d64, S.w, u3.w);
    u0 = n0; u1 = n1; u2 = n2; u3 = n3;
  }
}

// ---------------------------------------------------------------------------
// Phase C: o[u,i] = d_i^{u+1} * sum_j S_start[i][j] q_u[j]  + so[u,i]
// Writes FINAL scan output as bf16 (sob) for the MFMA out-projection.
// ---------------------------------------------------------------------------
__global__ __launch_bounds__(256) void scan_chunk_c(
    const float* __restrict__ qkv, const float* __restrict__ decay,
    const float* __restrict__ Sbuf, const float* __restrict__ so,
    __bf16* __restrict__ sob)
{
  __shared__ float Ss[64 * PAD];
  __shared__ float Qs[64 * PAD];
  __shared__ float l2d[64];

  const int tid = threadIdx.x;
  const int bc  = blockIdx.x;
  const int b   = bc >> 6;
  const int ch  = bc & 63;
  const int ti  = tid >> 4;
  const int tj  = tid & 15;

  #pragma unroll
  for (int it = 0; it < 4; ++it) {
    int idx = tid + it * 256;
    int row = idx >> 4, col4 = idx & 15;
    float4 s4 = *(const float4*)(Sbuf + (size_t)bc * 4096 + (size_t)row * 64 + col4 * 4);
    *ldsP(Ss, row, col4) = s4;
    float4 q4 = *(const float4*)(qkv + ((size_t)(b * Tt + ch * 64 + row)) * 192 + col4 * 4);
    *ldsP(Qs, row, col4) = q4;
  }
  if (tid < 64) {
    float d = 1.0f / (1.0f + expf(-decay[tid]));
    l2d[tid] = log2f(d);
  }
  __syncthreads();

  float acc[4][4] = {};
  #pragma unroll
  for (int j4 = 0; j4 < 16; ++j4) {
    float4 Q4[4], S4[4];
    #pragma unroll
    for (int r = 0; r < 4; ++r) Q4[r] = *ldsP(Qs, ti * 4 + r, j4);
    #pragma unroll
    for (int c = 0; c < 4; ++c) S4[c] = *ldsP(Ss, tj * 4 + c, j4);
    #pragma unroll
    for (int r = 0; r < 4; ++r)
      #pragma unroll
      for (int c = 0; c < 4; ++c) {
        acc[r][c] = fmaf(Q4[r].x, S4[c].x, acc[r][c]);
        acc[r][c] = fmaf(Q4[r].y, S4[c].y, acc[r][c]);
        acc[r][c] = fmaf(Q4[r].z, S4[c].z, acc[r][c]);
        acc[r][c] = fmaf(Q4[r].w, S4[c].w, acc[r][c]);
      }
  }

  #pragma unroll
  for (int r = 0; r < 4; ++r) {
    int u = ti * 4 + r;
    size_t row = (size_t)(b * Tt + ch * 64 + u);
    float4 prev = *(const float4*)(so + row * 64 + tj * 4);
    float e0 = exp2f((float)(u + 1) * l2d[tj * 4 + 0]);
    float e1 = exp2f((float)(u + 1) * l2d[tj * 4 + 1]);
    float e2 = exp2f((float)(u + 1) * l2d[tj * 4 + 2]);
    float e3 = exp2f((float)(u + 1) * l2d[tj * 4 + 3]);
    bf16x4v ov;
    ov[0] = (__bf16)fmaf(acc[r][0], e0, prev.x);
    ov[1] = (__bf16)fmaf(acc[r][1], e1, prev.y);
    ov[2] = (__bf16)fmaf(acc[r][2], e2, prev.z);
    ov[3] = (__bf16)fmaf(acc[r][3], e3, prev.w);
    *(bf16x4v*)(sob + row * 64 + tj * 4) = ov;
  }
}

// ---------------------------------------------------------------------------
// Kernel 3: out[M][1024] = x + sob[M][64] @ Wo^T + bo via MFMA.
// v4: 4-way j-split for occupancy. Block = 4 waves x 16 rows; each block
// covers cols jq*256..jq*256+255 (4 j-blocks of 64). Grid 2048 = 8 blk/CU.
// D-frags staged through per-wave 4KB XOR-swizzled LDS (wave-synchronous,
// no barriers) so x-load / out-store instructions cover 4 rows x 256B.
// ---------------------------------------------------------------------------
__global__ __launch_bounds__(256) void out_mfma(
    const float* __restrict__ x, const __bf16* __restrict__ sob,
    const __bf16* __restrict__ Wob, const float* __restrict__ bo,
    float* __restrict__ out)
{
  __shared__ float ps[4][16 * 64];   // per-wave staging, 4KB each

  const int bid = blockIdx.x;
  const int rb  = bid >> 2;          // 0..511 row-block (64 rows)
  const int jq  = bid & 3;           // column quarter (256 cols)
  const int w   = threadIdx.x >> 6;
  const int l   = threadIdx.x & 63;
  const int lr  = l & 15;
  const int lk  = l >> 4;
  const int m0  = rb * 64 + w * 16;  // wave's 16 rows
  const int er  = l >> 4;            // epilogue row group 0..3
  const int ec  = l & 15;            // epilogue col4

  // B operand: sob rows m0+lr (reused across the 4 j-blocks)
  const __bf16* bp = sob + (size_t)(m0 + lr) * 64 + lk * 8;
  bf16x8 bf0 = *(const bf16x8*)(bp);
  bf16x8 bf1 = *(const bf16x8*)(bp + 32);

  float* myps = ps[w];

  #pragma unroll
  for (int jj = 0; jj < 4; ++jj) {
    const int j0 = (jq * 4 + jj) * 64;

    // issue x loads early (hide HBM latency under MFMA+LDS)
    float4 xv[4];
    #pragma unroll
    for (int k = 0; k < 4; ++k)
      xv[k] = *(const float4*)(x + (size_t)(m0 + er + 4 * k) * 1024 + j0 + ec * 4);
    float4 b4 = *(const float4*)(bo + j0 + ec * 4);

    // A operands: Wob rows j (L2-resident), 4 j-frags x K=64
    const __bf16* ap = Wob + (size_t)(j0 + lr) * 64 + lk * 8;
    f32x4 acc[4];
    #pragma unroll
    for (int jf = 0; jf < 4; ++jf) {
      bf16x8 a0 = *(const bf16x8*)(ap + (size_t)jf * 16 * 64);
      bf16x8 a1 = *(const bf16x8*)(ap + (size_t)jf * 16 * 64 + 32);
      f32x4 t = {0.f, 0.f, 0.f, 0.f};
      t = __builtin_amdgcn_mfma_f32_16x16x32_bf16(a0, bf0, t, 0, 0, 0);
      t = __builtin_amdgcn_mfma_f32_16x16x32_bf16(a1, bf1, t, 0, 0, 0);
      acc[jf] = t;
    }

    // stage D-frags to LDS: thread at (row lr, col4 jf*4+lk), XOR-swizzled
    #pragma unroll
    for (int jf = 0; jf < 4; ++jf) {
      int c4 = jf * 4 + lk;
      float4 v = {acc[jf][0], acc[jf][1], acc[jf][2], acc[jf][3]};
      *(float4*)((char*)myps + lr * 256 + ((c4 * 16) ^ ((lr & 7) << 4))) = v;
    }

    // wave-synchronous readback (DS ops in-order within a wave), add, store
    #pragma unroll
    for (int k = 0; k < 4; ++k) {
      int r = er + 4 * k;
      float4 pv = *(const float4*)((char*)myps + r * 256 + ((ec * 16) ^ ((r & 7) << 4)));
      size_t m = (size_t)(m0 + r);
      float4 o;
      o.x = xv[k].x + pv.x + b4.x;
      o.y = xv[k].y + pv.y + b4.y;
      o.z = xv[k].z + pv.z + b4.z;
      o.w = xv[k].w + pv.w + b4.w;
      *(float4*)(out + m * 1024 + j0 + ec * 4) = o;
    }
  }
}

// ---------------------------------------------------------------------------
extern "C" void kernel_launch(void* const* d_in, const int* in_sizes, int n_in,
                              void* d_out, int out_size, void* d_ws, size_t ws_size,
                              hipStream_t stream)
{
  const float* x   = (const float*)d_in[0];
  const float* Wq  = (const float*)d_in[1];
  const float* bq  = (const float*)d_in[2];
  const float* Wk  = (const float*)d_in[3];
  const float* bk  = (const float*)d_in[4];
  const float* Wv  = (const float*)d_in[5];
  const float* bv  = (const float*)d_in[6];
  const float* dec = (const float*)d_in[7];
  const float* Wo  = (const float*)d_in[8];
  const float* bo  = (const float*)d_in[9];
  float* out = (float*)d_out;

  float*  qkv   = (float*)d_ws;                    // [M][192] fp32 = 25.2 MB
  float*  so    = qkv + (size_t)Mm * 192;          // [M][64]  fp32 =  8.4 MB
  float*  Ubuf  = so + (size_t)Mm * 64;            // [512][64][64] =  8.4 MB
  __bf16* sob   = (__bf16*)(Ubuf + (size_t)512 * 4096);  // [M][64] bf16 = 4.2 MB
  __bf16* Wqkvb = sob + (size_t)Mm * 64;           // [192][1024]
  __bf16* Wob   = Wqkvb + (size_t)192 * 1024;      // [1024][64]

  convert_w<<<768, 256, 0, stream>>>(Wq, Wk, Wv, Wo, Wqkvb, Wob);
  qkv_mfma<<<Mm / 64, 256, 0, stream>>>(x, Wqkvb, bq, bk, bv, qkv);
  scan_chunk_a<<<512, 256, 0, stream>>>(qkv, dec, Ubuf, so);
  scan_state<<<128, 64, 0, stream>>>(dec, Ubuf);
  scan_chunk_c<<<512, 256, 0, stream>>>(qkv, dec, Ubuf, so, sob);
  out_mfma<<<2048, 256, 0, stream>>>(x, sob, Wob, bo, out);
}

// Round 10
// 348.231 us; speedup vs baseline: 3.8034x; 1.0341x over previous
//
#include <hip/hip_runtime.h>
#include <cstdint>
#include <cstddef>
#include <cmath>

#define Bb 8
#define Tt 4096
#define Dd 1024
#define DS 64
#define Mm (Bb*Tt)   // 32768
#define PAD 68       // floats per LDS row (fp32 scan tiles)

typedef __bf16 bf16x8 __attribute__((ext_vector_type(8)));
typedef __bf16 bf16x4v __attribute__((ext_vector_type(4)));
typedef float f32x4 __attribute__((ext_vector_type(4)));

// float4 pointer into a [64][PAD] fp32 LDS tile, XOR-swizzled (scan kernels)
__device__ __forceinline__ float4* ldsP(float* buf, int row, int col4) {
  return (float4*)(buf + row * PAD + (((col4) ^ ((row >> 3) & 7)) << 2));
}

// ---------------------------------------------------------------------------
// convert_w: Wq|Wk|Wv (stacked [192][1024]) and Wo ([1024][64]) -> bf16
// ---------------------------------------------------------------------------
__global__ __launch_bounds__(256) void convert_w(
    const float* __restrict__ Wq, const float* __restrict__ Wk,
    const float* __restrict__ Wv, const float* __restrict__ Wo,
    __bf16* __restrict__ Wqkvb, __bf16* __restrict__ Wob)
{
  int idx = blockIdx.x * 256 + threadIdx.x;
  if (idx < 196608) {
    float v = (idx < 65536) ? Wq[idx]
            : (idx < 131072) ? Wk[idx - 65536] : Wv[idx - 131072];
    Wqkvb[idx] = (__bf16)v;
  }
  if (idx < 65536) Wob[idx] = (__bf16)Wo[idx];
}

// ---------------------------------------------------------------------------
// Kernel 1: QKV projection via MFMA, operand-swapped (A=W rows j, B=x rows m).
// Double-buffered LDS x staging (1 barrier / 64-K) + register double-buffer
// of W fragments (breaks the L2-load -> MFMA dependence chain).
// Output qkvb is bf16 [M][192] (halves store + downstream read traffic).
// ---------------------------------------------------------------------------
__global__ __launch_bounds__(256) void qkv_mfma(
    const float* __restrict__ x, const __bf16* __restrict__ Wb,
    const float* __restrict__ bq, const float* __restrict__ bk,
    const float* __restrict__ bv, __bf16* __restrict__ qkvb)
{
  __shared__ __bf16 xs[2][64 * 64];   // 2 x 8KB, XOR-swizzled

  const int tid = threadIdx.x;
  const int w   = tid >> 6;
  const int l   = tid & 63;
  const int m0  = blockIdx.x * 64;
  const int c0  = w * 48;
  const int lr  = l & 15;
  const int lk  = l >> 4;

  // staging role: rows (tid>>4)+16g (g=0..3), k-col4 = tid&15
  const int sr0 = tid >> 4;
  const int sc4 = tid & 15;
  const float* xsrc = x + (size_t)(m0 + sr0) * 1024 + sc4 * 4;

  f32x4 acc[3][4] = {};   // [jf][mf]

  // prologue: x tile 0 -> regs -> xs[0] (NT loads: x is stream-once here)
  f32x4 f[4];
  #pragma unroll
  for (int g = 0; g < 4; ++g)
    f[g] = __builtin_nontemporal_load((const f32x4*)(xsrc + (size_t)g * 16 * 1024));
  #pragma unroll
  for (int g = 0; g < 4; ++g) {
    bf16x4v h;
    h[0] = (__bf16)f[g][0]; h[1] = (__bf16)f[g][1];
    h[2] = (__bf16)f[g][2]; h[3] = (__bf16)f[g][3];
    int row = sr0 + 16 * g;
    *(bf16x4v*)((char*)xs[0] + row * 128 + ((sc4 * 8) ^ ((row & 7) << 4))) = h;
  }

  // W fragment register double-buffer (3 j-frags)
  const __bf16* wp = Wb + (size_t)(c0 + lr) * 1024 + lk * 8;
  bf16x8 wc0 = *(const bf16x8*)(wp + 0 * 16 * 1024);
  bf16x8 wc1 = *(const bf16x8*)(wp + 1 * 16 * 1024);
  bf16x8 wc2 = *(const bf16x8*)(wp + 2 * 16 * 1024);

  int cur = 0;
  for (int k0 = 0; k0 < 1024; k0 += 64) {
    const bool hasNext = (k0 + 64 < 1024);
    if (hasNext) {
      #pragma unroll
      for (int g = 0; g < 4; ++g)
        f[g] = __builtin_nontemporal_load(
            (const f32x4*)(xsrc + (size_t)g * 16 * 1024 + k0 + 64));
    }

    __syncthreads();   // xs[cur] writes visible; prior reads of xs[cur^1] done

    if (hasNext) {
      #pragma unroll
      for (int g = 0; g < 4; ++g) {
        bf16x4v h;
        h[0] = (__bf16)f[g][0]; h[1] = (__bf16)f[g][1];
        h[2] = (__bf16)f[g][2]; h[3] = (__bf16)f[g][3];
        int row = sr0 + 16 * g;
        *(bf16x4v*)((char*)xs[cur ^ 1] + row * 128 + ((sc4 * 8) ^ ((row & 7) << 4))) = h;
      }
    }

    #pragma unroll
    for (int ks = 0; ks < 2; ++ks) {
      const int knext = k0 + ks * 32 + 32;
      bf16x8 wn0, wn1, wn2;
      if (knext < 1024) {            // uniform branch; prefetch next W frags
        wn0 = *(const bf16x8*)(wp + 0 * 16 * 1024 + knext);
        wn1 = *(const bf16x8*)(wp + 1 * 16 * 1024 + knext);
        wn2 = *(const bf16x8*)(wp + 2 * 16 * 1024 + knext);
      }
      bf16x8 xf[4];
      #pragma unroll
      for (int mf = 0; mf < 4; ++mf) {
        int row = mf * 16 + lr;
        int boff = row * 128 + ((ks * 64 + lk * 16) ^ ((row & 7) << 4));
        xf[mf] = *(const bf16x8*)((const char*)xs[cur] + boff);
      }
      #pragma unroll
      for (int mf = 0; mf < 4; ++mf) {
        acc[0][mf] = __builtin_amdgcn_mfma_f32_16x16x32_bf16(wc0, xf[mf], acc[0][mf], 0, 0, 0);
        acc[1][mf] = __builtin_amdgcn_mfma_f32_16x16x32_bf16(wc1, xf[mf], acc[1][mf], 0, 0, 0);
        acc[2][mf] = __builtin_amdgcn_mfma_f32_16x16x32_bf16(wc2, xf[mf], acc[2][mf], 0, 0, 0);
      }
      if (knext < 1024) { wc0 = wn0; wc1 = wn1; wc2 = wn2; }
    }
    cur ^= 1;
  }

  // epilogue: j = c0 + jf*16 + lk*4 + r (contiguous bf16x4), m = mf*16 + lr
  #pragma unroll
  for (int jf = 0; jf < 3; ++jf) {
    int j0 = c0 + jf * 16 + lk * 4;
    const float* bsrc = (j0 < 64) ? (bq + j0)
                      : (j0 < 128) ? (bk + j0 - 64) : (bv + j0 - 128);
    float4 b4 = *(const float4*)bsrc;
    #pragma unroll
    for (int mf = 0; mf < 4; ++mf) {
      int m = m0 + mf * 16 + lr;
      bf16x4v o;
      o[0] = (__bf16)(acc[jf][mf][0] + b4.x);
      o[1] = (__bf16)(acc[jf][mf][1] + b4.y);
      o[2] = (__bf16)(acc[jf][mf][2] + b4.z);
      o[3] = (__bf16)(acc[jf][mf][3] + b4.w);
      *(bf16x4v*)(qkvb + (size_t)m * 192 + j0) = o;
    }
  }
}

// ---------------------------------------------------------------------------
// Phase A: per (b,chunk): G = causal(Q K^T) (stored transposed GT[s][u]),
//   Vt[s,i] = v_s[i] * d_i^{-s},
//   U[i,j]  = d_i^63 * sum_s Vt[s,i] K[s,j]      -> Ubuf
//   intra[u,i] = d_i^u * sum_s GT[s,u] Vt[s,i]   -> so (phase C adds to it)
// Input qkvb is bf16; converted to fp32 during LDS staging.
// ---------------------------------------------------------------------------
__global__ __launch_bounds__(256) void scan_chunk_a(
    const __bf16* __restrict__ qkvb, const float* __restrict__ decay,
    float* __restrict__ Ubuf, float* __restrict__ so)
{
  __shared__ float Qs[64 * PAD];   // later overwritten with GT
  __shared__ float Ks[64 * PAD];
  __shared__ float Vs[64 * PAD];   // scaled to Vt in place
  __shared__ float l2d[64];

  const int tid = threadIdx.x;
  const int bc  = blockIdx.x;          // b*64 + ch
  const int b   = bc >> 6;
  const int ch  = bc & 63;
  const int ti  = tid >> 4;
  const int tj  = tid & 15;

  const __bf16* base = qkvb + ((size_t)(b * Tt + ch * 64)) * 192;

  // stage 64 rows x 24 16B-chunks (8 Q, 8 K, 8 V) with bf16->fp32 convert
  #pragma unroll
  for (int it = 0; it < 6; ++it) {
    int idx = tid + it * 256;
    int row = idx / 24, fq = idx % 24;
    bf16x8 h = *(const bf16x8*)(base + (size_t)row * 192 + fq * 8);
    float4 lo = {(float)h[0], (float)h[1], (float)h[2], (float)h[3]};
    float4 hi = {(float)h[4], (float)h[5], (float)h[6], (float)h[7]};
    int seg = fq >> 3, c2 = (fq & 7) * 2;
    float* dst = (seg == 0) ? Qs : (seg == 1) ? Ks : Vs;
    *ldsP(dst, row, c2)     = lo;
    *ldsP(dst, row, c2 + 1) = hi;
  }
  if (tid < 64) {
    float d = 1.0f / (1.0f + expf(-decay[tid]));
    l2d[tid] = log2f(d);
  }
  __syncthreads();

  {
    int s = tid >> 2;
    #pragma unroll
    for (int g4 = 0; g4 < 4; ++g4) {
      int col4 = (tid & 3) * 4 + g4;
      float4* p = ldsP(Vs, s, col4);
      float4 v = *p;
      float e0 = exp2f(-(float)s * l2d[col4 * 4 + 0]);
      float e1 = exp2f(-(float)s * l2d[col4 * 4 + 1]);
      float e2 = exp2f(-(float)s * l2d[col4 * 4 + 2]);
      float e3 = exp2f(-(float)s * l2d[col4 * 4 + 3]);
      v.x *= e0; v.y *= e1; v.z *= e2; v.w *= e3;
      *p = v;
    }
  }

  float gval[4][4] = {};
  #pragma unroll
  for (int kk4 = 0; kk4 < 16; ++kk4) {
    float4 K4[4], Q4[4];
    #pragma unroll
    for (int r = 0; r < 4; ++r) K4[r] = *ldsP(Ks, ti * 4 + r, kk4);
    #pragma unroll
    for (int c = 0; c < 4; ++c) Q4[c] = *ldsP(Qs, tj * 4 + c, kk4);
    #pragma unroll
    for (int r = 0; r < 4; ++r)
      #pragma unroll
      for (int c = 0; c < 4; ++c) {
        gval[r][c] = fmaf(K4[r].x, Q4[c].x, gval[r][c]);
        gval[r][c] = fmaf(K4[r].y, Q4[c].y, gval[r][c]);
        gval[r][c] = fmaf(K4[r].z, Q4[c].z, gval[r][c]);
        gval[r][c] = fmaf(K4[r].w, Q4[c].w, gval[r][c]);
      }
  }
  #pragma unroll
  for (int r = 0; r < 4; ++r)
    #pragma unroll
    for (int c = 0; c < 4; ++c)
      if (ti * 4 + r > tj * 4 + c) gval[r][c] = 0.0f;

  __syncthreads();

  #pragma unroll
  for (int r = 0; r < 4; ++r) {
    float4 g4 = {gval[r][0], gval[r][1], gval[r][2], gval[r][3]};
    *ldsP(Qs, ti * 4 + r, tj) = g4;
  }
  __syncthreads();

  float uacc[4][4] = {};
  float oacc[4][4] = {};
  for (int s = 0; s < 64; ++s) {
    float4 Vti = *ldsP(Vs, s, ti);
    float4 Ktj = *ldsP(Ks, s, tj);
    float4 Gti = *ldsP(Qs, s, ti);
    float4 Vtj = *ldsP(Vs, s, tj);
    const float vi[4] = {Vti.x, Vti.y, Vti.z, Vti.w};
    const float kj[4] = {Ktj.x, Ktj.y, Ktj.z, Ktj.w};
    const float gu[4] = {Gti.x, Gti.y, Gti.z, Gti.w};
    const float vj[4] = {Vtj.x, Vtj.y, Vtj.z, Vtj.w};
    #pragma unroll
    for (int r = 0; r < 4; ++r)
      #pragma unroll
      for (int c = 0; c < 4; ++c) {
        uacc[r][c] = fmaf(vi[r], kj[c], uacc[r][c]);
        oacc[r][c] = fmaf(gu[r], vj[c], oacc[r][c]);
      }
  }

  #pragma unroll
  for (int r = 0; r < 4; ++r) {
    int i = ti * 4 + r;
    float d63 = exp2f(63.0f * l2d[i]);
    float4 o = {uacc[r][0] * d63, uacc[r][1] * d63,
                uacc[r][2] * d63, uacc[r][3] * d63};
    *(float4*)(Ubuf + ((size_t)bc * 64 + i) * 64 + tj * 4) = o;
  }
  #pragma unroll
  for (int r = 0; r < 4; ++r) {
    int u = ti * 4 + r;
    float e0 = exp2f((float)u * l2d[tj * 4 + 0]);
    float e1 = exp2f((float)u * l2d[tj * 4 + 1]);
    float e2 = exp2f((float)u * l2d[tj * 4 + 2]);
    float e3 = exp2f((float)u * l2d[tj * 4 + 3]);
    float4 o = {oacc[r][0] * e0, oacc[r][1] * e1,
                oacc[r][2] * e2, oacc[r][3] * e3};
    *(float4*)(so + ((size_t)(b * Tt + ch * 64 + u)) * 64 + tj * 4) = o;
  }
}

// ---------------------------------------------------------------------------
// Phase B: sequential over 64 chunks; in-place U -> S_start. 4-deep prefetch.
// ---------------------------------------------------------------------------
__global__ __launch_bounds__(64) void scan_state(
    const float* __restrict__ decay, float* __restrict__ Ubuf)
{
  const int b  = blockIdx.x >> 4;
  const int jq = blockIdx.x & 15;
  const int i  = threadIdx.x;

  float d = 1.0f / (1.0f + expf(-decay[i]));
  float d2 = d * d, d4 = d2 * d2, d8 = d4 * d4;
  float d16 = d8 * d8, d32 = d16 * d16, d64 = d32 * d32;

  float* base = Ubuf + ((size_t)b * 64) * 4096 + (size_t)i * 64 + jq * 4;

  float4 S = {0.f, 0.f, 0.f, 0.f};
  float4 u0 = *(const float4*)(base + 0 * 4096);
  float4 u1 = *(const float4*)(base + 1 * 4096);
  float4 u2 = *(const float4*)(base + 2 * 4096);
  float4 u3 = *(const float4*)(base + 3 * 4096);

  for (int c = 0; c < 64; c += 4) {
    float4 n0 = u0, n1 = u1, n2 = u2, n3 = u3;
    if (c + 4 < 64) {
      n0 = *(const float4*)(base + (size_t)(c + 4) * 4096);
      n1 = *(const float4*)(base + (size_t)(c + 5) * 4096);
      n2 = *(const float4*)(base + (size_t)(c + 6) * 4096);
      n3 = *(const float4*)(base + (size_t)(c + 7) * 4096);
    }
    *(float4*)(base + (size_t)(c + 0) * 4096) = S;
    S.x = fmaf(d64, S.x, u0.x); S.y = fmaf(d64, S.y, u0.y);
    S.z = fmaf(d64, S.z, u0.z); S.w = fmaf(d64, S.w, u0.w);
    *(float4*)(base + (size_t)(c + 1) * 4096) = S;
    S.x = fmaf(d64, S.x, u1.x); S.y = fmaf(d64, S.y, u1.y);
    S.z = fmaf(d64, S.z, u1.z); S.w = fmaf(d64, S.w, u1.w);
    *(float4*)(base + (size_t)(c + 2) * 4096) = S;
    S.x = fmaf(d64, S.x, u2.x); S.y = fmaf(d64, S.y, u2.y);
    S.z = fmaf(d64, S.z, u2.z); S.w = fmaf(d64, S.w, u2.w);
    *(float4*)(base + (size_t)(c + 3) * 4096) = S;
    S.x = fmaf(d64, S.x, u3.x); S.y = fmaf(d64, S.y, u3.y);
    S.z = fmaf(d64, S.z, u3.z); S.w = fmaf(d64, S.w, u3.w);
    u0 = n0; u1 = n1; u2 = n2; u3 = n3;
  }
}

// ---------------------------------------------------------------------------
// Phase C: o[u,i] = d_i^{u+1} * sum_j S_start[i][j] q_u[j]  + so[u,i]
// Q read from bf16 qkvb; writes FINAL scan output as bf16 (sob).
// ---------------------------------------------------------------------------
__global__ __launch_bounds__(256) void scan_chunk_c(
    const __bf16* __restrict__ qkvb, const float* __restrict__ decay,
    const float* __restrict__ Sbuf, const float* __restrict__ so,
    __bf16* __restrict__ sob)
{
  __shared__ float Ss[64 * PAD];
  __shared__ float Qs[64 * PAD];
  __shared__ float l2d[64];

  const int tid = threadIdx.x;
  const int bc  = blockIdx.x;
  const int b   = bc >> 6;
  const int ch  = bc & 63;
  const int ti  = tid >> 4;
  const int tj  = tid & 15;

  // stage S_start (fp32 64x64) and Q chunk (bf16 -> fp32)
  #pragma unroll
  for (int it = 0; it < 4; ++it) {
    int idx = tid + it * 256;
    int row = idx >> 4, col4 = idx & 15;
    float4 s4 = *(const float4*)(Sbuf + (size_t)bc * 4096 + (size_t)row * 64 + col4 * 4);
    *ldsP(Ss, row, col4) = s4;
  }
  #pragma unroll
  for (int it = 0; it < 2; ++it) {
    int idx = tid + it * 256;
    int row = idx >> 3, fq = idx & 7;
    bf16x8 h = *(const bf16x8*)(qkvb + ((size_t)(b * Tt + ch * 64 + row)) * 192 + fq * 8);
    float4 lo = {(float)h[0], (float)h[1], (float)h[2], (float)h[3]};
    float4 hi = {(float)h[4], (float)h[5], (float)h[6], (float)h[7]};
    *ldsP(Qs, row, fq * 2)     = lo;
    *ldsP(Qs, row, fq * 2 + 1) = hi;
  }
  if (tid < 64) {
    float d = 1.0f / (1.0f + expf(-decay[tid]));
    l2d[tid] = log2f(d);
  }
  __syncthreads();

  float acc[4][4] = {};
  #pragma unroll
  for (int j4 = 0; j4 < 16; ++j4) {
    float4 Q4[4], S4[4];
    #pragma unroll
    for (int r = 0; r < 4; ++r) Q4[r] = *ldsP(Qs, ti * 4 + r, j4);
    #pragma unroll
    for (int c = 0; c < 4; ++c) S4[c] = *ldsP(Ss, tj * 4 + c, j4);
    #pragma unroll
    for (int r = 0; r < 4; ++r)
      #pragma unroll
      for (int c = 0; c < 4; ++c) {
        acc[r][c] = fmaf(Q4[r].x, S4[c].x, acc[r][c]);
        acc[r][c] = fmaf(Q4[r].y, S4[c].y, acc[r][c]);
        acc[r][c] = fmaf(Q4[r].z, S4[c].z, acc[r][c]);
        acc[r][c] = fmaf(Q4[r].w, S4[c].w, acc[r][c]);
      }
  }

  #pragma unroll
  for (int r = 0; r < 4; ++r) {
    int u = ti * 4 + r;
    size_t row = (size_t)(b * Tt + ch * 64 + u);
    float4 prev = *(const float4*)(so + row * 64 + tj * 4);
    float e0 = exp2f((float)(u + 1) * l2d[tj * 4 + 0]);
    float e1 = exp2f((float)(u + 1) * l2d[tj * 4 + 1]);
    float e2 = exp2f((float)(u + 1) * l2d[tj * 4 + 2]);
    float e3 = exp2f((float)(u + 1) * l2d[tj * 4 + 3]);
    bf16x4v ov;
    ov[0] = (__bf16)fmaf(acc[r][0], e0, prev.x);
    ov[1] = (__bf16)fmaf(acc[r][1], e1, prev.y);
    ov[2] = (__bf16)fmaf(acc[r][2], e2, prev.z);
    ov[3] = (__bf16)fmaf(acc[r][3], e3, prev.w);
    *(bf16x4v*)(sob + row * 64 + tj * 4) = ov;
  }
}

// ---------------------------------------------------------------------------
// Kernel 3: out[M][1024] = x + sob[M][64] @ Wo^T + bo via MFMA.
// v5: explicit software pipeline over the 4 j-blocks (prefetch next x tile
// into named regs during MFMA+LDS), NT loads for x / NT stores for out.
// Block = 4 waves x 16 rows, cols jq*256..+255. Grid 2048.
// ---------------------------------------------------------------------------
__global__ __launch_bounds__(256) void out_mfma(
    const float* __restrict__ x, const __bf16* __restrict__ sob,
    const __bf16* __restrict__ Wob, const float* __restrict__ bo,
    float* __restrict__ out)
{
  __shared__ float ps[4][16 * 64];   // per-wave staging, 4KB each

  const int bid = blockIdx.x;
  const int rb  = bid >> 2;          // row-block (64 rows)
  const int jq  = bid & 3;           // column quarter (256 cols)
  const int w   = threadIdx.x >> 6;
  const int l   = threadIdx.x & 63;
  const int lr  = l & 15;
  const int lk  = l >> 4;
  const int m0  = rb * 64 + w * 16;  // wave's 16 rows
  const int er  = l >> 4;            // epilogue row group 0..3
  const int ec  = l & 15;            // epilogue col4

  // B operand: sob rows m0+lr (reused across the 4 j-blocks)
  const __bf16* bp = sob + (size_t)(m0 + lr) * 64 + lk * 8;
  bf16x8 bfr0 = *(const bf16x8*)(bp);
  bf16x8 bfr1 = *(const bf16x8*)(bp + 32);

  float* myps = ps[w];

  // prologue: x tile + bias for jj=0
  f32x4 cxv[4]; f32x4 cb4;
  {
    const int j0 = jq * 256;
    #pragma unroll
    for (int k = 0; k < 4; ++k)
      cxv[k] = __builtin_nontemporal_load(
          (const f32x4*)(x + (size_t)(m0 + er + 4 * k) * 1024 + j0 + ec * 4));
    cb4 = *(const f32x4*)(bo + j0 + ec * 4);
  }

  #pragma unroll
  for (int jj = 0; jj < 4; ++jj) {
    const int j0 = jq * 256 + jj * 64;

    // prefetch next j-block's x tile + bias (overlaps MFMA + LDS below)
    f32x4 nxv[4]; f32x4 nb4;
    if (jj < 3) {
      const int jn = j0 + 64;
      #pragma unroll
      for (int k = 0; k < 4; ++k)
        nxv[k] = __builtin_nontemporal_load(
            (const f32x4*)(x + (size_t)(m0 + er + 4 * k) * 1024 + jn + ec * 4));
      nb4 = *(const f32x4*)(bo + jn + ec * 4);
    }

    // A operands: Wob rows j (L2-resident), 4 j-frags x K=64
    const __bf16* ap = Wob + (size_t)(j0 + lr) * 64 + lk * 8;
    f32x4 acc[4];
    #pragma unroll
    for (int jf = 0; jf < 4; ++jf) {
      bf16x8 a0 = *(const bf16x8*)(ap + (size_t)jf * 16 * 64);
      bf16x8 a1 = *(const bf16x8*)(ap + (size_t)jf * 16 * 64 + 32);
      f32x4 t = {0.f, 0.f, 0.f, 0.f};
      t = __builtin_amdgcn_mfma_f32_16x16x32_bf16(a0, bfr0, t, 0, 0, 0);
      t = __builtin_amdgcn_mfma_f32_16x16x32_bf16(a1, bfr1, t, 0, 0, 0);
      acc[jf] = t;
    }

    // stage D-frags to LDS: thread at (row lr, col4 jf*4+lk), XOR-swizzled
    #pragma unroll
    for (int jf = 0; jf < 4; ++jf) {
      int c4 = jf * 4 + lk;
      float4 v = {acc[jf][0], acc[jf][1], acc[jf][2], acc[jf][3]};
      *(float4*)((char*)myps + lr * 256 + ((c4 * 16) ^ ((lr & 7) << 4))) = v;
    }

    // wave-synchronous readback (DS ops in-order within a wave), add, NT store
    #pragma unroll
    for (int k = 0; k < 4; ++k) {
      int r = er + 4 * k;
      float4 pv = *(const float4*)((char*)myps + r * 256 + ((ec * 16) ^ ((r & 7) << 4)));
      size_t m = (size_t)(m0 + r);
      f32x4 o;
      o[0] = cxv[k][0] + pv.x + cb4[0];
      o[1] = cxv[k][1] + pv.y + cb4[1];
      o[2] = cxv[k][2] + pv.z + cb4[2];
      o[3] = cxv[k][3] + pv.w + cb4[3];
      __builtin_nontemporal_store(o, (f32x4*)(out + m * 1024 + j0 + ec * 4));
    }

    if (jj < 3) {
      #pragma unroll
      for (int k = 0; k < 4; ++k) cxv[k] = nxv[k];
      cb4 = nb4;
    }
  }
}

// ---------------------------------------------------------------------------
extern "C" void kernel_launch(void* const* d_in, const int* in_sizes, int n_in,
                              void* d_out, int out_size, void* d_ws, size_t ws_size,
                              hipStream_t stream)
{
  const float* x   = (const float*)d_in[0];
  const float* Wq  = (const float*)d_in[1];
  const float* bq  = (const float*)d_in[2];
  const float* Wk  = (const float*)d_in[3];
  const float* bk  = (const float*)d_in[4];
  const float* Wv  = (const float*)d_in[5];
  const float* bv  = (const float*)d_in[6];
  const float* dec = (const float*)d_in[7];
  const float* Wo  = (const float*)d_in[8];
  const float* bo  = (const float*)d_in[9];
  float* out = (float*)d_out;

  __bf16* qkvb  = (__bf16*)d_ws;                        // [M][192] bf16 = 12.6 MB
  float*  so    = (float*)(qkvb + (size_t)Mm * 192);    // [M][64] fp32 =  8.4 MB
  float*  Ubuf  = so + (size_t)Mm * 64;                 // [512][64][64] = 8.4 MB
  __bf16* sob   = (__bf16*)(Ubuf + (size_t)512 * 4096); // [M][64] bf16 = 4.2 MB
  __bf16* Wqkvb = sob + (size_t)Mm * 64;                // [192][1024]
  __bf16* Wob   = Wqkvb + (size_t)192 * 1024;           // [1024][64]

  convert_w<<<768, 256, 0, stream>>>(Wq, Wk, Wv, Wo, Wqkvb, Wob);
  qkv_mfma<<<Mm / 64, 256, 0, stream>>>(x, Wqkvb, bq, bk, bv, qkvb);
  scan_chunk_a<<<512, 256, 0, stream>>>(qkvb, dec, Ubuf, so);
  scan_state<<<128, 64, 0, stream>>>(dec, Ubuf);
  scan_chunk_c<<<512, 256, 0, stream>>>(qkvb, dec, Ubuf, so, sob);
  out_mfma<<<2048, 256, 0, stream>>>(x, sob, Wob, bo, out);
}